// Round 1
// baseline (713.194 us; speedup 1.0000x reference)
//
#include <hip/hip_runtime.h>
#include <hip/hip_bf16.h>

#define N_NODES 50000
#define N_EDGES 800000
#define DIM     256
#define NLAYERS 4
#define EPS     1e-5f
#define SCAN_B  196   // ceil(50000/256)
#define MASK40  ((1ULL << 40) - 1)
#define EPACK_CAP (N_EDGES + 15 * N_NODES + 32)   // CSR padded to 16

typedef __bf16 bf16x8 __attribute__((ext_vector_type(8)));
typedef float  f32x4  __attribute__((ext_vector_type(4)));
typedef float  f32x2  __attribute__((ext_vector_type(2)));
typedef unsigned short u16x8 __attribute__((ext_vector_type(8)));
typedef unsigned short u16x4 __attribute__((ext_vector_type(4)));
typedef int            i32x4 __attribute__((ext_vector_type(4)));
typedef unsigned int   u32x2 __attribute__((ext_vector_type(2)));

__device__ __forceinline__ unsigned short f2b(float f) {
    __hip_bfloat16 h = __float2bfloat16(f);
    return __builtin_bit_cast(unsigned short, h);
}
__device__ __forceinline__ float b2f(unsigned short u) {
    unsigned int v = ((unsigned int)u) << 16;
    return __builtin_bit_cast(float, v);
}
__device__ __forceinline__ float gelu_exact(float x) {
    return 0.5f * x * (1.0f + erff(x * 0.70710678118654752f));
}
// pack 4 f32 -> 4 fp8 e4m3 (OCP on gfx950), RNE
__device__ __forceinline__ unsigned int pack_fp8x4(float a, float b, float c, float d) {
    int v = 0;
    v = __builtin_amdgcn_cvt_pk_fp8_f32(a, b, v, false);
    v = __builtin_amdgcn_cvt_pk_fp8_f32(c, d, v, true);
    return (unsigned int)v;
}

// ---- setup kernels ------------------------------------------------------
// One packed u64 atomic per edge: bits [40,64) = count, [0,40) = sum(w)*2^32.
__global__ __launch_bounds__(256) void hist_kernel(const int* __restrict__ dst,
                                                   const float* __restrict__ w,
                                                   unsigned long long* __restrict__ cnt64,
                                                   int* __restrict__ rank) {
    int e = blockIdx.x * 256 + threadIdx.x;
    if (e >= N_EDGES) return;
    int d = dst[e];
    unsigned long long wfix = (unsigned long long)(w[e] * 4294967296.0f);
    unsigned long long old = atomicAdd(&cnt64[d], (1ULL << 40) | wfix);
    rank[e] = (int)(old >> 40);
}

__global__ __launch_bounds__(256) void scan_a_kernel(const unsigned long long* __restrict__ cnt64,
                                                     float* __restrict__ dinv,
                                                     int* __restrict__ bsum) {
    __shared__ int l[256];
    int i = blockIdx.x * 256 + threadIdx.x;
    int pc = 0;
    if (i < N_NODES) {
        unsigned long long v = cnt64[i];
        int cnt = (int)(v >> 40);
        float sw = (float)(v & MASK40) * 2.3283064365386963e-10f;  // *2^-32
        dinv[i] = rsqrtf(1.0f + sw);
        pc = (cnt + 15) & ~15;
    }
    l[threadIdx.x] = pc;
    __syncthreads();
    for (int o = 128; o > 0; o >>= 1) {
        if (threadIdx.x < o) l[threadIdx.x] += l[threadIdx.x + o];
        __syncthreads();
    }
    if (threadIdx.x == 0) bsum[blockIdx.x] = l[0];
}

__global__ __launch_bounds__(256) void scan_b_kernel(const int* __restrict__ bsum,
                                                     int* __restrict__ boff,
                                                     int* __restrict__ rowptr) {
    __shared__ int l[256];
    int t = threadIdx.x;
    l[t] = (t < SCAN_B) ? bsum[t] : 0;
    __syncthreads();
    if (t == 0) {
        int run = 0;
        for (int j = 0; j < SCAN_B; ++j) { int v = l[j]; l[j] = run; run += v; }
        rowptr[N_NODES] = run;
    }
    __syncthreads();
    boff[t] = l[t];
}

__global__ __launch_bounds__(256) void scan_c_kernel(const unsigned long long* __restrict__ cnt64,
                                                     const int* __restrict__ boff,
                                                     int* __restrict__ rowptr) {
    __shared__ int l[256];
    int i = blockIdx.x * 256 + threadIdx.x;
    int pc = 0;
    if (i < N_NODES) {
        int cnt = (int)(cnt64[i] >> 40);
        pc = (cnt + 15) & ~15;
    }
    l[threadIdx.x] = pc;
    __syncthreads();
    if (threadIdx.x == 0) {
        int run = 0;
        for (int j = 0; j < 256; ++j) { int v = l[j]; l[j] = run; run += v; }
    }
    __syncthreads();
    if (i < N_NODES) rowptr[i] = boff[blockIdx.x] + l[threadIdx.x];
}

// No atomics: position = rowptr[dst] + rank.  epack.x = src byte-offset (src*256, fp8 rows).
__global__ __launch_bounds__(256) void fill_kernel(const int* __restrict__ src,
                                                   const int* __restrict__ dst,
                                                   const float* __restrict__ w,
                                                   const float* __restrict__ dinv,
                                                   const int* __restrict__ rowptr,
                                                   const int* __restrict__ rank,
                                                   int2* __restrict__ epack) {
    int e = blockIdx.x * 256 + threadIdx.x;
    if (e >= N_EDGES) return;
    int s = src[e], d = dst[e];
    float c = dinv[s] * w[e] * dinv[d];
    int p = rowptr[d] + rank[e];
    epack[p] = make_int2(s << 8, __float_as_int(c));
}

// conv_w[l][k][n] (l<4) and post_w[k][n] (slot 4) -> Wt[l][n][k] bf16
__global__ __launch_bounds__(256) void convw_kernel(const float* __restrict__ conv_w,
                                                    const float* __restrict__ post_w,
                                                    unsigned short* __restrict__ Wt) {
    int idx = blockIdx.x * 256 + threadIdx.x;
    if (idx >= 5 * 65536) return;
    int m = idx >> 16;
    int r = idx & 65535;
    int n = r >> 8;
    int k = r & 255;
    float v = (m < 4) ? conv_w[m * 65536 + k * 256 + n] : post_w[k * 256 + n];
    Wt[idx] = f2b(v);
}

// ---- per-layer kernels --------------------------------------------------
// wave-per-row: Z8 = fp8(LN0(emb)), Hbf = bf16(emb)  (used once)
__global__ __launch_bounds__(256) void ln_cast_kernel(const float* __restrict__ H,
                                                      const float* __restrict__ lnw,
                                                      const float* __restrict__ lnb,
                                                      unsigned char* __restrict__ Z8,
                                                      unsigned short* __restrict__ Hbf) {
    int row = blockIdx.x * 4 + (threadIdx.x >> 6);
    int lane = threadIdx.x & 63;
    const float4 x = *(const float4*)(H + (size_t)row * DIM + lane * 4);
    float s = x.x + x.y + x.z + x.w;
    for (int o = 32; o > 0; o >>= 1) s += __shfl_xor(s, o);
    float mu = s * (1.0f / DIM);
    float d0 = x.x - mu, d1 = x.y - mu, d2 = x.z - mu, d3 = x.w - mu;
    float v = d0 * d0 + d1 * d1 + d2 * d2 + d3 * d3;
    for (int o = 32; o > 0; o >>= 1) v += __shfl_xor(v, o);
    float rs = rsqrtf(v * (1.0f / DIM) + EPS);
    const float4 ww = *(const float4*)(lnw + lane * 4);
    const float4 bb = *(const float4*)(lnb + lane * 4);
    float z0 = d0 * rs * ww.x + bb.x;
    float z1 = d1 * rs * ww.y + bb.y;
    float z2 = d2 * rs * ww.z + bb.z;
    float z3 = d3 * rs * ww.w + bb.w;
    *(unsigned int*)(Z8 + (size_t)row * DIM + lane * 4) = pack_fp8x4(z0, z1, z2, z3);
    ushort4 h4;
    h4.x = f2b(x.x); h4.y = f2b(x.y); h4.z = f2b(x.z); h4.w = f2b(x.w);
    *(ushort4*)(Hbf + (size_t)row * DIM + lane * 4) = h4;
}

// Pure gather-aggregate (agg commutes with @W): AGG[dst] = sum coef * Z8[src]
// (+ self-loop dinv^2 * Z8[dst]). Wave per node, half-wave per edge, 8-deep
// chains per half. f32x2 accumulators -> v_pk_fma. Output bf16 rows.
__global__ __launch_bounds__(256) void agg_kernel(const unsigned char* __restrict__ Z8,
                                                  const int* __restrict__ rowptr,
                                                  const int2* __restrict__ epack,
                                                  const float* __restrict__ dinv,
                                                  unsigned short* __restrict__ AGG) {
    int node = blockIdx.x * 4 + (threadIdx.x >> 6);
    int lane = threadIdx.x & 63;
    int g = lane >> 5;           // half id
    int colB = (lane & 31) * 8;  // byte offset of this lane's 8 fp8 elems

    float di = dinv[node];
    float scg = (g == 0) ? di * di : 0.0f;   // self-loop only in half 0
    const u32x2 zs = *(const u32x2*)(Z8 + (size_t)node * DIM + colB);
    f32x2 a0, a1, a2, a3;
    {
        f32x2 p0 = __builtin_amdgcn_cvt_pk_f32_fp8(zs[0], false);
        f32x2 p1 = __builtin_amdgcn_cvt_pk_f32_fp8(zs[0], true);
        f32x2 p2 = __builtin_amdgcn_cvt_pk_f32_fp8(zs[1], false);
        f32x2 p3 = __builtin_amdgcn_cvt_pk_f32_fp8(zs[1], true);
        a0 = scg * p0; a1 = scg * p1; a2 = scg * p2; a3 = scg * p3;
    }

    int e0 = rowptr[node], e1 = rowptr[node + 1];
    for (int e = e0; e < e1; e += 16) {
        const int2* pp = epack + e + 8 * g;
        const i32x4 q0 = __builtin_nontemporal_load((const i32x4*)pp);        // edges 0,1
        const i32x4 q1 = __builtin_nontemporal_load((const i32x4*)(pp + 2));  // edges 2,3
        const i32x4 q2 = __builtin_nontemporal_load((const i32x4*)(pp + 4));  // edges 4,5
        const i32x4 q3 = __builtin_nontemporal_load((const i32x4*)(pp + 6));  // edges 6,7
        const u32x2 v0 = *(const u32x2*)(Z8 + q0[0] + colB);
        const u32x2 v1 = *(const u32x2*)(Z8 + q0[2] + colB);
        const u32x2 v2 = *(const u32x2*)(Z8 + q1[0] + colB);
        const u32x2 v3 = *(const u32x2*)(Z8 + q1[2] + colB);
        const u32x2 v4 = *(const u32x2*)(Z8 + q2[0] + colB);
        const u32x2 v5 = *(const u32x2*)(Z8 + q2[2] + colB);
        const u32x2 v6 = *(const u32x2*)(Z8 + q3[0] + colB);
        const u32x2 v7 = *(const u32x2*)(Z8 + q3[2] + colB);
        float c0 = __int_as_float(q0[1]), c1 = __int_as_float(q0[3]);
        float c2 = __int_as_float(q1[1]), c3 = __int_as_float(q1[3]);
        float c4 = __int_as_float(q2[1]), c5 = __int_as_float(q2[3]);
        float c6 = __int_as_float(q3[1]), c7 = __int_as_float(q3[3]);
        #pragma unroll
        for (int h = 0; h < 8; ++h) {
            u32x2 vv; float cc;
            switch (h) {
                case 0: vv = v0; cc = c0; break;
                case 1: vv = v1; cc = c1; break;
                case 2: vv = v2; cc = c2; break;
                case 3: vv = v3; cc = c3; break;
                case 4: vv = v4; cc = c4; break;
                case 5: vv = v5; cc = c5; break;
                case 6: vv = v6; cc = c6; break;
                default: vv = v7; cc = c7; break;
            }
            f32x2 p0 = __builtin_amdgcn_cvt_pk_f32_fp8(vv[0], false);
            f32x2 p1 = __builtin_amdgcn_cvt_pk_f32_fp8(vv[0], true);
            f32x2 p2 = __builtin_amdgcn_cvt_pk_f32_fp8(vv[1], false);
            f32x2 p3 = __builtin_amdgcn_cvt_pk_f32_fp8(vv[1], true);
            a0 += cc * p0; a1 += cc * p1; a2 += cc * p2; a3 += cc * p3;
        }
    }
    float a[8] = {a0[0], a0[1], a1[0], a1[1], a2[0], a2[1], a3[0], a3[1]};
    #pragma unroll
    for (int j = 0; j < 8; ++j) a[j] += __shfl_xor(a[j], 32);

    if (g == 0) {
        u16x8 z;
        #pragma unroll
        for (int j = 0; j < 8; ++j) z[j] = f2b(a[j]);
        __builtin_nontemporal_store(z, (u16x8*)(AGG + (size_t)node * DIM + colB));
    }
}

// ---- fused GEMM: C = AGG @ W + b -> GELU -> + Hbf -> (Hbf', LN -> fp8 Z8')
// 64 nodes x 256 chans per block; wave w owns chans [64w, 64w+64).
__global__ __launch_bounds__(256) void gemm_fused_kernel(const unsigned short* __restrict__ A,
                                                         const unsigned short* __restrict__ Bt,
                                                         const float* __restrict__ bias,
                                                         unsigned short* __restrict__ Hbf,
                                                         const float* __restrict__ lnw,
                                                         const float* __restrict__ lnb,
                                                         unsigned char* __restrict__ Z8,
                                                         int doLN) {
    __shared__ float s_sum[4][64];
    __shared__ float s_sq[4][64];
    int tid = threadIdx.x;
    int wave = tid >> 6;
    int lane = tid & 63;
    int q = lane >> 4;
    int c16 = lane & 15;
    int mbase = blockIdx.x * 64;
    int cbase = wave * 64;

    int arow[4];
    const unsigned short* aptr[4];
    #pragma unroll
    for (int nt = 0; nt < 4; ++nt) {
        int row = mbase + nt * 16 + c16;
        arow[nt] = (row >= N_NODES) ? (N_NODES - 1) : row;
        aptr[nt] = A + (size_t)arow[nt] * DIM;
    }
    const unsigned short* wptr[4];
    #pragma unroll
    for (int ct = 0; ct < 4; ++ct)
        wptr[ct] = Bt + (size_t)(cbase + ct * 16 + c16) * DIM;

    f32x4 acc[4][4] = {};
    #pragma unroll 1
    for (int k0 = 0; k0 < DIM; k0 += 32) {
        bf16x8 nf[4], wf[4];
        #pragma unroll
        for (int nt = 0; nt < 4; ++nt)
            nf[nt] = __builtin_bit_cast(bf16x8, *(const u16x8*)(aptr[nt] + k0 + q * 8));
        #pragma unroll
        for (int ct = 0; ct < 4; ++ct)
            wf[ct] = __builtin_bit_cast(bf16x8, *(const u16x8*)(wptr[ct] + k0 + q * 8));
        #pragma unroll
        for (int nt = 0; nt < 4; ++nt)
            #pragma unroll
            for (int ct = 0; ct < 4; ++ct)
                acc[nt][ct] = __builtin_amdgcn_mfma_f32_16x16x32_bf16(wf[ct], nf[nt], acc[nt][ct], 0, 0, 0);
    }

    // epilogue: bias + exact GELU + residual; acc reused in place as h_new
    float psum[4], psq[4];
    #pragma unroll
    for (int nt = 0; nt < 4; ++nt) {
        psum[nt] = 0.0f; psq[nt] = 0.0f;
        #pragma unroll
        for (int ct = 0; ct < 4; ++ct) {
            int chan = cbase + ct * 16 + q * 4;
            const f32x4 bb = *(const f32x4*)(bias + chan);
            const u16x4 hv = __builtin_nontemporal_load(
                (const u16x4*)(Hbf + (size_t)arow[nt] * DIM + chan));
            #pragma unroll
            for (int j = 0; j < 4; ++j) {
                float v = acc[nt][ct][j] + bb[j];
                float hn = gelu_exact(v) + b2f(hv[j]);
                acc[nt][ct][j] = hn;
                psum[nt] += hn;
                psq[nt] += hn * hn;
            }
        }
    }

    float mu[4], rs[4];
    if (doLN) {
        #pragma unroll
        for (int nt = 0; nt < 4; ++nt) {
            psum[nt] += __shfl_xor(psum[nt], 16);
            psum[nt] += __shfl_xor(psum[nt], 32);
            psq[nt]  += __shfl_xor(psq[nt], 16);
            psq[nt]  += __shfl_xor(psq[nt], 32);
        }
        if (q == 0) {
            #pragma unroll
            for (int nt = 0; nt < 4; ++nt) {
                s_sum[wave][nt * 16 + c16] = psum[nt];
                s_sq[wave][nt * 16 + c16]  = psq[nt];
            }
        }
        __syncthreads();
        #pragma unroll
        for (int nt = 0; nt < 4; ++nt) {
            int li = nt * 16 + c16;
            float ts = s_sum[0][li] + s_sum[1][li] + s_sum[2][li] + s_sum[3][li];
            float tq = s_sq[0][li] + s_sq[1][li] + s_sq[2][li] + s_sq[3][li];
            float m = ts * (1.0f / DIM);
            float var = fmaxf(tq * (1.0f / DIM) - m * m, 0.0f);
            mu[nt] = m;
            rs[nt] = rsqrtf(var + EPS);
        }
    }

    #pragma unroll
    for (int nt = 0; nt < 4; ++nt) {
        int node = mbase + nt * 16 + c16;
        if (node >= N_NODES) continue;
        #pragma unroll
        for (int ct = 0; ct < 4; ++ct) {
            int chan = cbase + ct * 16 + q * 4;
            u16x4 hw;
            hw[0] = f2b(acc[nt][ct][0]);
            hw[1] = f2b(acc[nt][ct][1]);
            hw[2] = f2b(acc[nt][ct][2]);
            hw[3] = f2b(acc[nt][ct][3]);
            __builtin_nontemporal_store(hw, (u16x4*)(Hbf + (size_t)node * DIM + chan));
            if (doLN) {
                const f32x4 ww = *(const f32x4*)(lnw + chan);
                const f32x4 lb = *(const f32x4*)(lnb + chan);
                float y0 = (acc[nt][ct][0] - mu[nt]) * rs[nt] * ww[0] + lb[0];
                float y1 = (acc[nt][ct][1] - mu[nt]) * rs[nt] * ww[1] + lb[1];
                float y2 = (acc[nt][ct][2] - mu[nt]) * rs[nt] * ww[2] + lb[2];
                float y3 = (acc[nt][ct][3] - mu[nt]) * rs[nt] * ww[3] + lb[3];
                *(unsigned int*)(Z8 + (size_t)node * DIM + chan) = pack_fp8x4(y0, y1, y2, y3);
            }
        }
    }
}

// ---- final GEMM: out = Hbf @ post_w + post_b (fp32 out) -----------------
__global__ __launch_bounds__(256) void gemm_out_kernel(const unsigned short* __restrict__ A,
                                                       const unsigned short* __restrict__ Bt,
                                                       float* __restrict__ C,
                                                       const float* __restrict__ bias) {
    int tid = threadIdx.x;
    int wave = tid >> 6;
    int lane = tid & 63;
    int q = lane >> 4;
    int c16 = lane & 15;
    int mbase = blockIdx.x * 64;
    int cbase = wave * 64;

    const unsigned short* aptr[4];
    #pragma unroll
    for (int nt = 0; nt < 4; ++nt) {
        int row = mbase + nt * 16 + c16;
        if (row >= N_NODES) row = N_NODES - 1;
        aptr[nt] = A + (size_t)row * DIM;
    }
    const unsigned short* wptr[4];
    #pragma unroll
    for (int ct = 0; ct < 4; ++ct)
        wptr[ct] = Bt + (size_t)(cbase + ct * 16 + c16) * DIM;

    f32x4 acc[4][4] = {};
    #pragma unroll 1
    for (int k0 = 0; k0 < DIM; k0 += 32) {
        bf16x8 nf[4], wf[4];
        #pragma unroll
        for (int nt = 0; nt < 4; ++nt)
            nf[nt] = __builtin_bit_cast(bf16x8, *(const u16x8*)(aptr[nt] + k0 + q * 8));
        #pragma unroll
        for (int ct = 0; ct < 4; ++ct)
            wf[ct] = __builtin_bit_cast(bf16x8, *(const u16x8*)(wptr[ct] + k0 + q * 8));
        #pragma unroll
        for (int nt = 0; nt < 4; ++nt)
            #pragma unroll
            for (int ct = 0; ct < 4; ++ct)
                acc[nt][ct] = __builtin_amdgcn_mfma_f32_16x16x32_bf16(wf[ct], nf[nt], acc[nt][ct], 0, 0, 0);
    }

    float4 bb[4];
    #pragma unroll
    for (int ct = 0; ct < 4; ++ct)
        bb[ct] = *(const float4*)(bias + cbase + ct * 16 + q * 4);
    #pragma unroll
    for (int nt = 0; nt < 4; ++nt) {
        int node = mbase + nt * 16 + c16;
        if (node >= N_NODES) continue;
        #pragma unroll
        for (int ct = 0; ct < 4; ++ct) {
            int chan = cbase + ct * 16 + q * 4;
            float4 o;
            o.x = acc[nt][ct][0] + bb[ct].x;
            o.y = acc[nt][ct][1] + bb[ct].y;
            o.z = acc[nt][ct][2] + bb[ct].z;
            o.w = acc[nt][ct][3] + bb[ct].w;
            *(float4*)(C + (size_t)node * DIM + chan) = o;
        }
    }
}

// ---- launch -------------------------------------------------------------
extern "C" void kernel_launch(void* const* d_in, const int* in_sizes, int n_in,
                              void* d_out, int out_size, void* d_ws, size_t ws_size,
                              hipStream_t stream) {
    const int*   ei     = (const int*)d_in[1];
    const int*   src    = ei;
    const int*   dst    = ei + N_EDGES;
    const float* ew     = (const float*)d_in[2];
    const float* emb    = (const float*)d_in[3];
    const float* ln_w   = (const float*)d_in[4];
    const float* ln_b   = (const float*)d_in[5];
    const float* conv_w = (const float*)d_in[6];
    const float* conv_b = (const float*)d_in[7];
    const float* post_w = (const float*)d_in[8];
    const float* post_b = (const float*)d_in[9];
    float* out = (float*)d_out;

    char* w = (char*)d_ws;
    size_t off = 0;
    auto alloc = [&](size_t bytes) -> char* {
        char* p = w + off;
        off += (bytes + 255) & ~(size_t)255;
        return p;
    };
    unsigned long long* cnt64 = (unsigned long long*)alloc((size_t)N_NODES * 8);
    float* dinv   = (float*)alloc((size_t)N_NODES * 4);
    int*   rank   = (int*)alloc((size_t)N_EDGES * 4);
    int*   rowptr = (int*)alloc((size_t)(N_NODES + 1) * 4);
    int*   bsum   = (int*)alloc(256 * 4);
    int*   boff   = (int*)alloc(256 * 4);
    int2*  epack  = (int2*)alloc((size_t)EPACK_CAP * 8);
    unsigned short* Wt    = (unsigned short*)alloc((size_t)5 * 65536 * 2);
    unsigned short* AGG16 = (unsigned short*)alloc((size_t)N_NODES * DIM * 2);
    unsigned char*  Z8    = (unsigned char*)alloc((size_t)N_NODES * DIM);
    unsigned short* Hbf   = (unsigned short*)alloc((size_t)N_NODES * DIM * 2);

    hipMemsetAsync(cnt64, 0, (size_t)N_NODES * 8, stream);
    hipMemsetAsync(epack, 0, (size_t)EPACK_CAP * 8, stream);
    hist_kernel<<<N_EDGES / 256, 256, 0, stream>>>(dst, ew, cnt64, rank);
    scan_a_kernel<<<SCAN_B, 256, 0, stream>>>(cnt64, dinv, bsum);
    scan_b_kernel<<<1, 256, 0, stream>>>(bsum, boff, rowptr);
    scan_c_kernel<<<SCAN_B, 256, 0, stream>>>(cnt64, boff, rowptr);
    fill_kernel<<<N_EDGES / 256, 256, 0, stream>>>(src, dst, ew, dinv, rowptr, rank, epack);
    convw_kernel<<<(5 * 65536) / 256, 256, 0, stream>>>(conv_w, post_w, Wt);

    const int GEMM_GRID = (N_NODES + 63) / 64;  // 782
    ln_cast_kernel<<<N_NODES / 4, 256, 0, stream>>>(emb, ln_w, ln_b, Z8, Hbf);
    for (int l = 0; l < NLAYERS; ++l) {
        agg_kernel<<<N_NODES / 4, 256, 0, stream>>>(Z8, rowptr, epack, dinv, AGG16);
        int doLN = (l < NLAYERS - 1) ? 1 : 0;
        const float* nlw = doLN ? (ln_w + (l + 1) * DIM) : ln_w;
        const float* nlb = doLN ? (ln_b + (l + 1) * DIM) : ln_b;
        gemm_fused_kernel<<<GEMM_GRID, 256, 0, stream>>>(AGG16, Wt + (size_t)l * 65536,
                                                         conv_b + (size_t)l * DIM, Hbf,
                                                         nlw, nlb, Z8, doLN);
    }
    gemm_out_kernel<<<GEMM_GRID, 256, 0, stream>>>(Hbf, Wt + (size_t)4 * 65536, out, post_b);
}

// Round 2
// 701.548 us; speedup vs baseline: 1.0166x; 1.0166x over previous
//
#include <hip/hip_runtime.h>
#include <hip/hip_bf16.h>

#define N_NODES 50000
#define N_EDGES 800000
#define DIM     256
#define NLAYERS 4
#define EPS     1e-5f
#define SCAN_B  196   // ceil(50000/256)
#define MASK40  ((1ULL << 40) - 1)
#define EPACK_CAP (N_EDGES + 15 * N_NODES + 32)   // CSR padded to 16
#define STRIDE  260   // LDS row stride (elems): 256 + 4 pad -> bank decorrelation

typedef __bf16 bf16x8 __attribute__((ext_vector_type(8)));
typedef float  f32x4  __attribute__((ext_vector_type(4)));
typedef float  f32x2  __attribute__((ext_vector_type(2)));
typedef unsigned short u16x8 __attribute__((ext_vector_type(8)));
typedef unsigned short u16x4 __attribute__((ext_vector_type(4)));
typedef int            i32x4 __attribute__((ext_vector_type(4)));
typedef unsigned int   u32x2 __attribute__((ext_vector_type(2)));

__device__ __forceinline__ unsigned short f2b(float f) {
    __hip_bfloat16 h = __float2bfloat16(f);
    return __builtin_bit_cast(unsigned short, h);
}
__device__ __forceinline__ float b2f(unsigned short u) {
    unsigned int v = ((unsigned int)u) << 16;
    return __builtin_bit_cast(float, v);
}
__device__ __forceinline__ float gelu_exact(float x) {
    return 0.5f * x * (1.0f + erff(x * 0.70710678118654752f));
}
// pack 4 f32 -> 4 fp8 e4m3 (OCP on gfx950), RNE
__device__ __forceinline__ unsigned int pack_fp8x4(float a, float b, float c, float d) {
    int v = 0;
    v = __builtin_amdgcn_cvt_pk_fp8_f32(a, b, v, false);
    v = __builtin_amdgcn_cvt_pk_fp8_f32(c, d, v, true);
    return (unsigned int)v;
}

// ---- setup kernels ------------------------------------------------------
__global__ __launch_bounds__(256) void hist_kernel(const int* __restrict__ dst,
                                                   const float* __restrict__ w,
                                                   unsigned long long* __restrict__ cnt64,
                                                   int* __restrict__ rank) {
    int e = blockIdx.x * 256 + threadIdx.x;
    if (e >= N_EDGES) return;
    int d = dst[e];
    unsigned long long wfix = (unsigned long long)(w[e] * 4294967296.0f);
    unsigned long long old = atomicAdd(&cnt64[d], (1ULL << 40) | wfix);
    rank[e] = (int)(old >> 40);
}

__global__ __launch_bounds__(256) void scan_a_kernel(const unsigned long long* __restrict__ cnt64,
                                                     float* __restrict__ dinv,
                                                     int* __restrict__ bsum) {
    __shared__ int l[256];
    int i = blockIdx.x * 256 + threadIdx.x;
    int pc = 0;
    if (i < N_NODES) {
        unsigned long long v = cnt64[i];
        int cnt = (int)(v >> 40);
        float sw = (float)(v & MASK40) * 2.3283064365386963e-10f;  // *2^-32
        dinv[i] = rsqrtf(1.0f + sw);
        pc = (cnt + 15) & ~15;
    }
    l[threadIdx.x] = pc;
    __syncthreads();
    for (int o = 128; o > 0; o >>= 1) {
        if (threadIdx.x < o) l[threadIdx.x] += l[threadIdx.x + o];
        __syncthreads();
    }
    if (threadIdx.x == 0) bsum[blockIdx.x] = l[0];
}

__global__ __launch_bounds__(256) void scan_b_kernel(const int* __restrict__ bsum,
                                                     int* __restrict__ boff,
                                                     int* __restrict__ rowptr) {
    __shared__ int l[256];
    int t = threadIdx.x;
    l[t] = (t < SCAN_B) ? bsum[t] : 0;
    __syncthreads();
    if (t == 0) {
        int run = 0;
        for (int j = 0; j < SCAN_B; ++j) { int v = l[j]; l[j] = run; run += v; }
        rowptr[N_NODES] = run;
    }
    __syncthreads();
    boff[t] = l[t];
}

__global__ __launch_bounds__(256) void scan_c_kernel(const unsigned long long* __restrict__ cnt64,
                                                     const int* __restrict__ boff,
                                                     int* __restrict__ rowptr) {
    __shared__ int l[256];
    int i = blockIdx.x * 256 + threadIdx.x;
    int pc = 0;
    if (i < N_NODES) {
        int cnt = (int)(cnt64[i] >> 40);
        pc = (cnt + 15) & ~15;
    }
    l[threadIdx.x] = pc;
    __syncthreads();
    if (threadIdx.x == 0) {
        int run = 0;
        for (int j = 0; j < 256; ++j) { int v = l[j]; l[j] = run; run += v; }
    }
    __syncthreads();
    if (i < N_NODES) rowptr[i] = boff[blockIdx.x] + l[threadIdx.x];
}

// No atomics: position = rowptr[dst] + rank.  epack.x = src byte-offset (src*256, fp8 rows).
__global__ __launch_bounds__(256) void fill_kernel(const int* __restrict__ src,
                                                   const int* __restrict__ dst,
                                                   const float* __restrict__ w,
                                                   const float* __restrict__ dinv,
                                                   const int* __restrict__ rowptr,
                                                   const int* __restrict__ rank,
                                                   int2* __restrict__ epack) {
    int e = blockIdx.x * 256 + threadIdx.x;
    if (e >= N_EDGES) return;
    int s = src[e], d = dst[e];
    float c = dinv[s] * w[e] * dinv[d];
    int p = rowptr[d] + rank[e];
    epack[p] = make_int2(s << 8, __float_as_int(c));
}

// conv_w[l][k][n] (l<4) and post_w[k][n] (slot 4) -> Wt[l][n][k] bf16
__global__ __launch_bounds__(256) void convw_kernel(const float* __restrict__ conv_w,
                                                    const float* __restrict__ post_w,
                                                    unsigned short* __restrict__ Wt) {
    int idx = blockIdx.x * 256 + threadIdx.x;
    if (idx >= 5 * 65536) return;
    int m = idx >> 16;
    int r = idx & 65535;
    int n = r >> 8;
    int k = r & 255;
    float v = (m < 4) ? conv_w[m * 65536 + k * 256 + n] : post_w[k * 256 + n];
    Wt[idx] = f2b(v);
}

// ---- per-layer kernels --------------------------------------------------
// wave-per-row: Z8 = fp8(LN0(emb)), Hbf = bf16(emb)  (used once)
__global__ __launch_bounds__(256) void ln_cast_kernel(const float* __restrict__ H,
                                                      const float* __restrict__ lnw,
                                                      const float* __restrict__ lnb,
                                                      unsigned char* __restrict__ Z8,
                                                      unsigned short* __restrict__ Hbf) {
    int row = blockIdx.x * 4 + (threadIdx.x >> 6);
    int lane = threadIdx.x & 63;
    const float4 x = *(const float4*)(H + (size_t)row * DIM + lane * 4);
    float s = x.x + x.y + x.z + x.w;
    for (int o = 32; o > 0; o >>= 1) s += __shfl_xor(s, o);
    float mu = s * (1.0f / DIM);
    float d0 = x.x - mu, d1 = x.y - mu, d2 = x.z - mu, d3 = x.w - mu;
    float v = d0 * d0 + d1 * d1 + d2 * d2 + d3 * d3;
    for (int o = 32; o > 0; o >>= 1) v += __shfl_xor(v, o);
    float rs = rsqrtf(v * (1.0f / DIM) + EPS);
    const float4 ww = *(const float4*)(lnw + lane * 4);
    const float4 bb = *(const float4*)(lnb + lane * 4);
    float z0 = d0 * rs * ww.x + bb.x;
    float z1 = d1 * rs * ww.y + bb.y;
    float z2 = d2 * rs * ww.z + bb.z;
    float z3 = d3 * rs * ww.w + bb.w;
    *(unsigned int*)(Z8 + (size_t)row * DIM + lane * 4) = pack_fp8x4(z0, z1, z2, z3);
    ushort4 h4;
    h4.x = f2b(x.x); h4.y = f2b(x.y); h4.z = f2b(x.z); h4.w = f2b(x.w);
    *(ushort4*)(Hbf + (size_t)row * DIM + lane * 4) = h4;
}

// Pure gather-aggregate (agg commutes with @W): AGG[dst] = sum coef * Z8[src]
// (+ self-loop dinv^2 * Z8[dst]). Wave per node, half-wave per edge, 8-deep
// chains per half. f32x2 accumulators -> v_pk_fma. Output bf16 rows.
__global__ __launch_bounds__(256) void agg_kernel(const unsigned char* __restrict__ Z8,
                                                  const int* __restrict__ rowptr,
                                                  const int2* __restrict__ epack,
                                                  const float* __restrict__ dinv,
                                                  unsigned short* __restrict__ AGG) {
    int node = blockIdx.x * 4 + (threadIdx.x >> 6);
    int lane = threadIdx.x & 63;
    int g = lane >> 5;           // half id
    int colB = (lane & 31) * 8;  // byte offset of this lane's 8 fp8 elems

    float di = dinv[node];
    float scg = (g == 0) ? di * di : 0.0f;   // self-loop only in half 0
    const u32x2 zs = *(const u32x2*)(Z8 + (size_t)node * DIM + colB);
    f32x2 a0, a1, a2, a3;
    {
        f32x2 p0 = __builtin_amdgcn_cvt_pk_f32_fp8(zs[0], false);
        f32x2 p1 = __builtin_amdgcn_cvt_pk_f32_fp8(zs[0], true);
        f32x2 p2 = __builtin_amdgcn_cvt_pk_f32_fp8(zs[1], false);
        f32x2 p3 = __builtin_amdgcn_cvt_pk_f32_fp8(zs[1], true);
        a0 = scg * p0; a1 = scg * p1; a2 = scg * p2; a3 = scg * p3;
    }

    int e0 = rowptr[node], e1 = rowptr[node + 1];
    for (int e = e0; e < e1; e += 16) {
        const int2* pp = epack + e + 8 * g;
        const i32x4 q0 = *(const i32x4*)pp;        // edges 0,1
        const i32x4 q1 = *(const i32x4*)(pp + 2);  // edges 2,3
        const i32x4 q2 = *(const i32x4*)(pp + 4);  // edges 4,5
        const i32x4 q3 = *(const i32x4*)(pp + 6);  // edges 6,7
        const u32x2 v0 = *(const u32x2*)(Z8 + q0[0] + colB);
        const u32x2 v1 = *(const u32x2*)(Z8 + q0[2] + colB);
        const u32x2 v2 = *(const u32x2*)(Z8 + q1[0] + colB);
        const u32x2 v3 = *(const u32x2*)(Z8 + q1[2] + colB);
        const u32x2 v4 = *(const u32x2*)(Z8 + q2[0] + colB);
        const u32x2 v5 = *(const u32x2*)(Z8 + q2[2] + colB);
        const u32x2 v6 = *(const u32x2*)(Z8 + q3[0] + colB);
        const u32x2 v7 = *(const u32x2*)(Z8 + q3[2] + colB);
        float c0 = __int_as_float(q0[1]), c1 = __int_as_float(q0[3]);
        float c2 = __int_as_float(q1[1]), c3 = __int_as_float(q1[3]);
        float c4 = __int_as_float(q2[1]), c5 = __int_as_float(q2[3]);
        float c6 = __int_as_float(q3[1]), c7 = __int_as_float(q3[3]);
        #pragma unroll
        for (int h = 0; h < 8; ++h) {
            u32x2 vv; float cc;
            switch (h) {
                case 0: vv = v0; cc = c0; break;
                case 1: vv = v1; cc = c1; break;
                case 2: vv = v2; cc = c2; break;
                case 3: vv = v3; cc = c3; break;
                case 4: vv = v4; cc = c4; break;
                case 5: vv = v5; cc = c5; break;
                case 6: vv = v6; cc = c6; break;
                default: vv = v7; cc = c7; break;
            }
            f32x2 p0 = __builtin_amdgcn_cvt_pk_f32_fp8(vv[0], false);
            f32x2 p1 = __builtin_amdgcn_cvt_pk_f32_fp8(vv[0], true);
            f32x2 p2 = __builtin_amdgcn_cvt_pk_f32_fp8(vv[1], false);
            f32x2 p3 = __builtin_amdgcn_cvt_pk_f32_fp8(vv[1], true);
            a0 += cc * p0; a1 += cc * p1; a2 += cc * p2; a3 += cc * p3;
        }
    }
    float a[8] = {a0[0], a0[1], a1[0], a1[1], a2[0], a2[1], a3[0], a3[1]};
    #pragma unroll
    for (int j = 0; j < 8; ++j) a[j] += __shfl_xor(a[j], 32);

    if (g == 0) {
        u16x8 z;
        #pragma unroll
        for (int j = 0; j < 8; ++j) z[j] = f2b(a[j]);
        *(u16x8*)(AGG + (size_t)node * DIM + colB) = z;
    }
}

// ---- fused GEMM: C = AGG @ W -> LDS (bf16, node-major) -> per-node epilogue
// bias + exact GELU + residual (Hbf rw) + optional LN -> fp8 Z8.
// All epilogue global IO is row-contiguous: thread t owns (node t>>2, 64-chan
// chunk t&3) -> 128B Hbf read/write, 64B Z8 write per thread.
__global__ __launch_bounds__(256) void gemm_fused_kernel(const unsigned short* __restrict__ A,
                                                         const unsigned short* __restrict__ Bt,
                                                         const float* __restrict__ bias,
                                                         unsigned short* __restrict__ Hbf,
                                                         const float* __restrict__ lnw,
                                                         const float* __restrict__ lnb,
                                                         unsigned char* __restrict__ Z8,
                                                         int doLN) {
    __shared__ unsigned short stile[64 * STRIDE];   // 33.3 KB, bf16 pre-bias acc
    int tid = threadIdx.x;
    int wave = tid >> 6;
    int lane = tid & 63;
    int q = lane >> 4;
    int c16 = lane & 15;
    int mbase = blockIdx.x * 64;
    int cbase = wave * 64;

    const unsigned short* aptr[4];
    #pragma unroll
    for (int nt = 0; nt < 4; ++nt) {
        int row = mbase + nt * 16 + c16;
        if (row >= N_NODES) row = N_NODES - 1;
        aptr[nt] = A + (size_t)row * DIM;
    }
    const unsigned short* wptr[4];
    #pragma unroll
    for (int ct = 0; ct < 4; ++ct)
        wptr[ct] = Bt + (size_t)(cbase + ct * 16 + c16) * DIM;

    f32x4 acc[4][4] = {};
    #pragma unroll 1
    for (int k0 = 0; k0 < DIM; k0 += 32) {
        bf16x8 nf[4], wf[4];
        #pragma unroll
        for (int nt = 0; nt < 4; ++nt)
            nf[nt] = __builtin_bit_cast(bf16x8, *(const u16x8*)(aptr[nt] + k0 + q * 8));
        #pragma unroll
        for (int ct = 0; ct < 4; ++ct)
            wf[ct] = __builtin_bit_cast(bf16x8, *(const u16x8*)(wptr[ct] + k0 + q * 8));
        #pragma unroll
        for (int nt = 0; nt < 4; ++nt)
            #pragma unroll
            for (int ct = 0; ct < 4; ++ct)
                acc[nt][ct] = __builtin_amdgcn_mfma_f32_16x16x32_bf16(wf[ct], nf[nt], acc[nt][ct], 0, 0, 0);
    }

    // stage pre-bias acc as bf16 (tighter than the fp8 path that passed before)
    #pragma unroll
    for (int nt = 0; nt < 4; ++nt) {
        int row = nt * 16 + c16;
        #pragma unroll
        for (int ct = 0; ct < 4; ++ct) {
            int col = cbase + ct * 16 + q * 4;
            u16x4 pk;
            pk[0] = f2b(acc[nt][ct][0]);
            pk[1] = f2b(acc[nt][ct][1]);
            pk[2] = f2b(acc[nt][ct][2]);
            pk[3] = f2b(acc[nt][ct][3]);
            *(u16x4*)&stile[row * STRIDE + col] = pk;
        }
    }
    __syncthreads();

    // node-major drain: thread -> (node r, 64-chan chunk ck)
    int r  = tid >> 2;
    int ck = tid & 3;
    int node = mbase + r;
    if (node < N_NODES) {
        const int cb = ck * 64;
        float h[64];
        float psum = 0.0f, psq = 0.0f;
        #pragma unroll
        for (int i = 0; i < 8; ++i) {
            const u16x8 sv = *(const u16x8*)&stile[r * STRIDE + cb + i * 8];
            const f32x4 b0 = *(const f32x4*)(bias + cb + i * 8);
            const f32x4 b1 = *(const f32x4*)(bias + cb + i * 8 + 4);
            const u16x8 hv = *(const u16x8*)(Hbf + (size_t)node * DIM + cb + i * 8);
            #pragma unroll
            for (int j = 0; j < 8; ++j) {
                float v = b2f(sv[j]) + (j < 4 ? b0[j] : b1[j - 4]);
                float hn = gelu_exact(v) + b2f(hv[j]);
                h[i * 8 + j] = hn;
                psum += hn;
                psq += hn * hn;
            }
        }
        // residual write (always)
        #pragma unroll
        for (int i = 0; i < 8; ++i) {
            u16x8 hw;
            #pragma unroll
            for (int j = 0; j < 8; ++j) hw[j] = f2b(h[i * 8 + j]);
            *(u16x8*)(Hbf + (size_t)node * DIM + cb + i * 8) = hw;
        }
        if (doLN) {
            psum += __shfl_xor(psum, 1);
            psum += __shfl_xor(psum, 2);
            psq  += __shfl_xor(psq, 1);
            psq  += __shfl_xor(psq, 2);
            float mu = psum * (1.0f / DIM);
            float var = fmaxf(psq * (1.0f / DIM) - mu * mu, 0.0f);
            float rs = rsqrtf(var + EPS);
            #pragma unroll
            for (int i2 = 0; i2 < 4; ++i2) {
                int c0 = cb + i2 * 16;
                unsigned int pk[4];
                #pragma unroll
                for (int k = 0; k < 4; ++k) {
                    const f32x4 ww = *(const f32x4*)(lnw + c0 + k * 4);
                    const f32x4 lb = *(const f32x4*)(lnb + c0 + k * 4);
                    int hb = i2 * 16 + k * 4;
                    float y0 = (h[hb + 0] - mu) * rs * ww[0] + lb[0];
                    float y1 = (h[hb + 1] - mu) * rs * ww[1] + lb[1];
                    float y2 = (h[hb + 2] - mu) * rs * ww[2] + lb[2];
                    float y3 = (h[hb + 3] - mu) * rs * ww[3] + lb[3];
                    pk[k] = pack_fp8x4(y0, y1, y2, y3);
                }
                uint4 st = make_uint4(pk[0], pk[1], pk[2], pk[3]);
                *(uint4*)(Z8 + (size_t)node * DIM + c0) = st;
            }
        }
    }
}

// ---- final GEMM: out = Hbf @ post_w + post_b (fp32 out) -----------------
// Operand-swapped MFMA -> D[node][chan]: stores quarter-wave 64B contiguous.
__global__ __launch_bounds__(256) void gemm_out_kernel(const unsigned short* __restrict__ A,
                                                       const unsigned short* __restrict__ Bt,
                                                       float* __restrict__ C,
                                                       const float* __restrict__ bias) {
    int tid = threadIdx.x;
    int wave = tid >> 6;
    int lane = tid & 63;
    int q = lane >> 4;
    int c16 = lane & 15;
    int mbase = blockIdx.x * 64;
    int cbase = wave * 64;

    const unsigned short* aptr[4];
    #pragma unroll
    for (int nt = 0; nt < 4; ++nt) {
        int row = mbase + nt * 16 + c16;
        if (row >= N_NODES) row = N_NODES - 1;
        aptr[nt] = A + (size_t)row * DIM;
    }
    const unsigned short* wptr[4];
    #pragma unroll
    for (int ct = 0; ct < 4; ++ct)
        wptr[ct] = Bt + (size_t)(cbase + ct * 16 + c16) * DIM;

    f32x4 acc[4][4] = {};
    #pragma unroll 1
    for (int k0 = 0; k0 < DIM; k0 += 32) {
        bf16x8 nf[4], wf[4];
        #pragma unroll
        for (int nt = 0; nt < 4; ++nt)
            nf[nt] = __builtin_bit_cast(bf16x8, *(const u16x8*)(aptr[nt] + k0 + q * 8));
        #pragma unroll
        for (int ct = 0; ct < 4; ++ct)
            wf[ct] = __builtin_bit_cast(bf16x8, *(const u16x8*)(wptr[ct] + k0 + q * 8));
        #pragma unroll
        for (int nt = 0; nt < 4; ++nt)
            #pragma unroll
            for (int ct = 0; ct < 4; ++ct)
                acc[nt][ct] = __builtin_amdgcn_mfma_f32_16x16x32_bf16(nf[nt], wf[ct], acc[nt][ct], 0, 0, 0);
    }

    float bb[4];
    #pragma unroll
    for (int ct = 0; ct < 4; ++ct)
        bb[ct] = bias[cbase + ct * 16 + c16];
    #pragma unroll
    for (int nt = 0; nt < 4; ++nt) {
        #pragma unroll
        for (int j = 0; j < 4; ++j) {
            int node = mbase + nt * 16 + q * 4 + j;
            if (node >= N_NODES) continue;
            #pragma unroll
            for (int ct = 0; ct < 4; ++ct) {
                int chan = cbase + ct * 16 + c16;
                C[(size_t)node * DIM + chan] = acc[nt][ct][j] + bb[ct];
            }
        }
    }
}

// ---- launch -------------------------------------------------------------
extern "C" void kernel_launch(void* const* d_in, const int* in_sizes, int n_in,
                              void* d_out, int out_size, void* d_ws, size_t ws_size,
                              hipStream_t stream) {
    const int*   ei     = (const int*)d_in[1];
    const int*   src    = ei;
    const int*   dst    = ei + N_EDGES;
    const float* ew     = (const float*)d_in[2];
    const float* emb    = (const float*)d_in[3];
    const float* ln_w   = (const float*)d_in[4];
    const float* ln_b   = (const float*)d_in[5];
    const float* conv_w = (const float*)d_in[6];
    const float* conv_b = (const float*)d_in[7];
    const float* post_w = (const float*)d_in[8];
    const float* post_b = (const float*)d_in[9];
    float* out = (float*)d_out;

    char* w = (char*)d_ws;
    size_t off = 0;
    auto alloc = [&](size_t bytes) -> char* {
        char* p = w + off;
        off += (bytes + 255) & ~(size_t)255;
        return p;
    };
    unsigned long long* cnt64 = (unsigned long long*)alloc((size_t)N_NODES * 8);
    float* dinv   = (float*)alloc((size_t)N_NODES * 4);
    int*   rank   = (int*)alloc((size_t)N_EDGES * 4);
    int*   rowptr = (int*)alloc((size_t)(N_NODES + 1) * 4);
    int*   bsum   = (int*)alloc(256 * 4);
    int*   boff   = (int*)alloc(256 * 4);
    int2*  epack  = (int2*)alloc((size_t)EPACK_CAP * 8);
    unsigned short* Wt    = (unsigned short*)alloc((size_t)5 * 65536 * 2);
    unsigned short* AGG16 = (unsigned short*)alloc((size_t)N_NODES * DIM * 2);
    unsigned char*  Z8    = (unsigned char*)alloc((size_t)N_NODES * DIM);
    unsigned short* Hbf   = (unsigned short*)alloc((size_t)N_NODES * DIM * 2);

    hipMemsetAsync(cnt64, 0, (size_t)N_NODES * 8, stream);
    hipMemsetAsync(epack, 0, (size_t)EPACK_CAP * 8, stream);
    hist_kernel<<<N_EDGES / 256, 256, 0, stream>>>(dst, ew, cnt64, rank);
    scan_a_kernel<<<SCAN_B, 256, 0, stream>>>(cnt64, dinv, bsum);
    scan_b_kernel<<<1, 256, 0, stream>>>(bsum, boff, rowptr);
    scan_c_kernel<<<SCAN_B, 256, 0, stream>>>(cnt64, boff, rowptr);
    fill_kernel<<<N_EDGES / 256, 256, 0, stream>>>(src, dst, ew, dinv, rowptr, rank, epack);
    convw_kernel<<<(5 * 65536) / 256, 256, 0, stream>>>(conv_w, post_w, Wt);

    const int GEMM_GRID = (N_NODES + 63) / 64;  // 782
    ln_cast_kernel<<<N_NODES / 4, 256, 0, stream>>>(emb, ln_w, ln_b, Z8, Hbf);
    for (int l = 0; l < NLAYERS; ++l) {
        agg_kernel<<<N_NODES / 4, 256, 0, stream>>>(Z8, rowptr, epack, dinv, AGG16);
        int doLN = (l < NLAYERS - 1) ? 1 : 0;
        const float* nlw = doLN ? (ln_w + (l + 1) * DIM) : ln_w;
        const float* nlb = doLN ? (ln_b + (l + 1) * DIM) : ln_b;
        gemm_fused_kernel<<<GEMM_GRID, 256, 0, stream>>>(AGG16, Wt + (size_t)l * 65536,
                                                         conv_b + (size_t)l * DIM, Hbf,
                                                         nlw, nlb, Z8, doLN);
    }
    gemm_out_kernel<<<GEMM_GRID, 256, 0, stream>>>(Hbf, Wt + (size_t)4 * 65536, out, post_b);
}

// Round 3
// 653.291 us; speedup vs baseline: 1.0917x; 1.0739x over previous
//
#include <hip/hip_runtime.h>
#include <hip/hip_bf16.h>

#define N_NODES 50000
#define N_EDGES 800000
#define DIM     256
#define NLAYERS 4
#define EPS     1e-5f
#define SCAN_B  196   // ceil(50000/256)
#define MASK40  ((1ULL << 40) - 1)
#define EPACK_CAP (N_EDGES + 15 * N_NODES + 32)   // CSR padded to 16
#define STRIDE  260   // LDS row stride (elems): 256 + 4 pad

typedef __bf16 bf16x8 __attribute__((ext_vector_type(8)));
typedef float  f32x4  __attribute__((ext_vector_type(4)));
typedef float  f32x2  __attribute__((ext_vector_type(2)));
typedef unsigned short u16x8 __attribute__((ext_vector_type(8)));
typedef unsigned short u16x4 __attribute__((ext_vector_type(4)));
typedef int            i32x4 __attribute__((ext_vector_type(4)));
typedef unsigned int   u32x2 __attribute__((ext_vector_type(2)));

__device__ __forceinline__ unsigned short f2b(float f) {
    __hip_bfloat16 h = __float2bfloat16(f);
    return __builtin_bit_cast(unsigned short, h);
}
__device__ __forceinline__ float b2f(unsigned short u) {
    unsigned int v = ((unsigned int)u) << 16;
    return __builtin_bit_cast(float, v);
}
__device__ __forceinline__ float gelu_exact(float x) {
    return 0.5f * x * (1.0f + erff(x * 0.70710678118654752f));
}
// pack 4 f32 -> 4 fp8 e4m3 (OCP on gfx950), RNE
__device__ __forceinline__ unsigned int pack_fp8x4(float a, float b, float c, float d) {
    int v = 0;
    v = __builtin_amdgcn_cvt_pk_fp8_f32(a, b, v, false);
    v = __builtin_amdgcn_cvt_pk_fp8_f32(c, d, v, true);
    return (unsigned int)v;
}

// ---- setup kernels ------------------------------------------------------
__global__ __launch_bounds__(256) void hist_kernel(const int* __restrict__ dst,
                                                   const float* __restrict__ w,
                                                   unsigned long long* __restrict__ cnt64,
                                                   int* __restrict__ rank) {
    int e = blockIdx.x * 256 + threadIdx.x;
    if (e >= N_EDGES) return;
    int d = dst[e];
    unsigned long long wfix = (unsigned long long)(w[e] * 4294967296.0f);
    unsigned long long old = atomicAdd(&cnt64[d], (1ULL << 40) | wfix);
    rank[e] = (int)(old >> 40);
}

__global__ __launch_bounds__(256) void scan_a_kernel(const unsigned long long* __restrict__ cnt64,
                                                     float* __restrict__ dinv,
                                                     int* __restrict__ bsum) {
    __shared__ int l[256];
    int i = blockIdx.x * 256 + threadIdx.x;
    int pc = 0;
    if (i < N_NODES) {
        unsigned long long v = cnt64[i];
        int cnt = (int)(v >> 40);
        float sw = (float)(v & MASK40) * 2.3283064365386963e-10f;  // *2^-32
        dinv[i] = rsqrtf(1.0f + sw);
        pc = (cnt + 15) & ~15;
    }
    l[threadIdx.x] = pc;
    __syncthreads();
    for (int o = 128; o > 0; o >>= 1) {
        if (threadIdx.x < o) l[threadIdx.x] += l[threadIdx.x + o];
        __syncthreads();
    }
    if (threadIdx.x == 0) bsum[blockIdx.x] = l[0];
}

__global__ __launch_bounds__(256) void scan_b_kernel(const int* __restrict__ bsum,
                                                     int* __restrict__ boff,
                                                     int* __restrict__ rowptr) {
    __shared__ int l[256];
    int t = threadIdx.x;
    l[t] = (t < SCAN_B) ? bsum[t] : 0;
    __syncthreads();
    if (t == 0) {
        int run = 0;
        for (int j = 0; j < SCAN_B; ++j) { int v = l[j]; l[j] = run; run += v; }
        rowptr[N_NODES] = run;
    }
    __syncthreads();
    boff[t] = l[t];
}

__global__ __launch_bounds__(256) void scan_c_kernel(const unsigned long long* __restrict__ cnt64,
                                                     const int* __restrict__ boff,
                                                     int* __restrict__ rowptr) {
    __shared__ int l[256];
    int i = blockIdx.x * 256 + threadIdx.x;
    int pc = 0;
    if (i < N_NODES) {
        int cnt = (int)(cnt64[i] >> 40);
        pc = (cnt + 15) & ~15;
    }
    l[threadIdx.x] = pc;
    __syncthreads();
    if (threadIdx.x == 0) {
        int run = 0;
        for (int j = 0; j < 256; ++j) { int v = l[j]; l[j] = run; run += v; }
    }
    __syncthreads();
    if (i < N_NODES) rowptr[i] = boff[blockIdx.x] + l[threadIdx.x];
}

// No atomics: position = rowptr[dst] + rank.  epack.x = src byte-offset (src*256, fp8 rows).
__global__ __launch_bounds__(256) void fill_kernel(const int* __restrict__ src,
                                                   const int* __restrict__ dst,
                                                   const float* __restrict__ w,
                                                   const float* __restrict__ dinv,
                                                   const int* __restrict__ rowptr,
                                                   const int* __restrict__ rank,
                                                   int2* __restrict__ epack) {
    int e = blockIdx.x * 256 + threadIdx.x;
    if (e >= N_EDGES) return;
    int s = src[e], d = dst[e];
    float c = dinv[s] * w[e] * dinv[d];
    int p = rowptr[d] + rank[e];
    epack[p] = make_int2(s << 8, __float_as_int(c));
}

// conv_w[l][k][n] (l<4) and post_w[k][n] (slot 4) -> Wt[l][n][k] bf16
__global__ __launch_bounds__(256) void convw_kernel(const float* __restrict__ conv_w,
                                                    const float* __restrict__ post_w,
                                                    unsigned short* __restrict__ Wt) {
    int idx = blockIdx.x * 256 + threadIdx.x;
    if (idx >= 5 * 65536) return;
    int m = idx >> 16;
    int r = idx & 65535;
    int n = r >> 8;
    int k = r & 255;
    float v = (m < 4) ? conv_w[m * 65536 + k * 256 + n] : post_w[k * 256 + n];
    Wt[idx] = f2b(v);
}

// ---- per-layer kernels --------------------------------------------------
// wave-per-row: Z8 = fp8(LN0(emb)), Hbf = bf16(emb)  (used once)
__global__ __launch_bounds__(256) void ln_cast_kernel(const float* __restrict__ H,
                                                      const float* __restrict__ lnw,
                                                      const float* __restrict__ lnb,
                                                      unsigned char* __restrict__ Z8,
                                                      unsigned short* __restrict__ Hbf) {
    int row = blockIdx.x * 4 + (threadIdx.x >> 6);
    int lane = threadIdx.x & 63;
    const float4 x = *(const float4*)(H + (size_t)row * DIM + lane * 4);
    float s = x.x + x.y + x.z + x.w;
    for (int o = 32; o > 0; o >>= 1) s += __shfl_xor(s, o);
    float mu = s * (1.0f / DIM);
    float d0 = x.x - mu, d1 = x.y - mu, d2 = x.z - mu, d3 = x.w - mu;
    float v = d0 * d0 + d1 * d1 + d2 * d2 + d3 * d3;
    for (int o = 32; o > 0; o >>= 1) v += __shfl_xor(v, o);
    float rs = rsqrtf(v * (1.0f / DIM) + EPS);
    const float4 ww = *(const float4*)(lnw + lane * 4);
    const float4 bb = *(const float4*)(lnb + lane * 4);
    float z0 = d0 * rs * ww.x + bb.x;
    float z1 = d1 * rs * ww.y + bb.y;
    float z2 = d2 * rs * ww.z + bb.z;
    float z3 = d3 * rs * ww.w + bb.w;
    *(unsigned int*)(Z8 + (size_t)row * DIM + lane * 4) = pack_fp8x4(z0, z1, z2, z3);
    ushort4 h4;
    h4.x = f2b(x.x); h4.y = f2b(x.y); h4.z = f2b(x.z); h4.w = f2b(x.w);
    *(ushort4*)(Hbf + (size_t)row * DIM + lane * 4) = h4;
}

// Pure gather-aggregate: AGG[dst] = sum coef * Z8[src] (+ self-loop).
__global__ __launch_bounds__(256) void agg_kernel(const unsigned char* __restrict__ Z8,
                                                  const int* __restrict__ rowptr,
                                                  const int2* __restrict__ epack,
                                                  const float* __restrict__ dinv,
                                                  unsigned short* __restrict__ AGG) {
    int node = blockIdx.x * 4 + (threadIdx.x >> 6);
    int lane = threadIdx.x & 63;
    int g = lane >> 5;           // half id
    int colB = (lane & 31) * 8;  // byte offset of this lane's 8 fp8 elems

    float di = dinv[node];
    float scg = (g == 0) ? di * di : 0.0f;   // self-loop only in half 0
    const u32x2 zs = *(const u32x2*)(Z8 + (size_t)node * DIM + colB);
    f32x2 a0, a1, a2, a3;
    {
        f32x2 p0 = __builtin_amdgcn_cvt_pk_f32_fp8(zs[0], false);
        f32x2 p1 = __builtin_amdgcn_cvt_pk_f32_fp8(zs[0], true);
        f32x2 p2 = __builtin_amdgcn_cvt_pk_f32_fp8(zs[1], false);
        f32x2 p3 = __builtin_amdgcn_cvt_pk_f32_fp8(zs[1], true);
        a0 = scg * p0; a1 = scg * p1; a2 = scg * p2; a3 = scg * p3;
    }

    int e0 = rowptr[node], e1 = rowptr[node + 1];
    for (int e = e0; e < e1; e += 16) {
        const int2* pp = epack + e + 8 * g;
        const i32x4 q0 = *(const i32x4*)pp;        // edges 0,1
        const i32x4 q1 = *(const i32x4*)(pp + 2);  // edges 2,3
        const i32x4 q2 = *(const i32x4*)(pp + 4);  // edges 4,5
        const i32x4 q3 = *(const i32x4*)(pp + 6);  // edges 6,7
        const u32x2 v0 = *(const u32x2*)(Z8 + q0[0] + colB);
        const u32x2 v1 = *(const u32x2*)(Z8 + q0[2] + colB);
        const u32x2 v2 = *(const u32x2*)(Z8 + q1[0] + colB);
        const u32x2 v3 = *(const u32x2*)(Z8 + q1[2] + colB);
        const u32x2 v4 = *(const u32x2*)(Z8 + q2[0] + colB);
        const u32x2 v5 = *(const u32x2*)(Z8 + q2[2] + colB);
        const u32x2 v6 = *(const u32x2*)(Z8 + q3[0] + colB);
        const u32x2 v7 = *(const u32x2*)(Z8 + q3[2] + colB);
        float c0 = __int_as_float(q0[1]), c1 = __int_as_float(q0[3]);
        float c2 = __int_as_float(q1[1]), c3 = __int_as_float(q1[3]);
        float c4 = __int_as_float(q2[1]), c5 = __int_as_float(q2[3]);
        float c6 = __int_as_float(q3[1]), c7 = __int_as_float(q3[3]);
        #pragma unroll
        for (int h = 0; h < 8; ++h) {
            u32x2 vv; float cc;
            switch (h) {
                case 0: vv = v0; cc = c0; break;
                case 1: vv = v1; cc = c1; break;
                case 2: vv = v2; cc = c2; break;
                case 3: vv = v3; cc = c3; break;
                case 4: vv = v4; cc = c4; break;
                case 5: vv = v5; cc = c5; break;
                case 6: vv = v6; cc = c6; break;
                default: vv = v7; cc = c7; break;
            }
            f32x2 p0 = __builtin_amdgcn_cvt_pk_f32_fp8(vv[0], false);
            f32x2 p1 = __builtin_amdgcn_cvt_pk_f32_fp8(vv[0], true);
            f32x2 p2 = __builtin_amdgcn_cvt_pk_f32_fp8(vv[1], false);
            f32x2 p3 = __builtin_amdgcn_cvt_pk_f32_fp8(vv[1], true);
            a0 += cc * p0; a1 += cc * p1; a2 += cc * p2; a3 += cc * p3;
        }
    }
    float a[8] = {a0[0], a0[1], a1[0], a1[1], a2[0], a2[1], a3[0], a3[1]};
    #pragma unroll
    for (int j = 0; j < 8; ++j) a[j] += __shfl_xor(a[j], 32);

    if (g == 0) {
        u16x8 z;
        #pragma unroll
        for (int j = 0; j < 8; ++j) z[j] = f2b(a[j]);
        *(u16x8*)(AGG + (size_t)node * DIM + colB) = z;
    }
}

// ---- fused GEMM: 32 nodes x 256 chans per block (grid 1563), 2-deep
// K-pipeline, LDS transpose, 8-threads-per-node epilogue.
__global__ __launch_bounds__(256, 4) void gemm_fused_kernel(const unsigned short* __restrict__ A,
                                                            const unsigned short* __restrict__ Bt,
                                                            const float* __restrict__ bias,
                                                            unsigned short* __restrict__ Hbf,
                                                            const float* __restrict__ lnw,
                                                            const float* __restrict__ lnb,
                                                            unsigned char* __restrict__ Z8,
                                                            int doLN) {
    __shared__ unsigned short stile[32 * STRIDE];   // 16.6 KB, bf16 pre-bias acc
    int tid = threadIdx.x;
    int wave = tid >> 6;
    int lane = tid & 63;
    int q = lane >> 4;
    int c16 = lane & 15;
    int mbase = blockIdx.x * 32;
    int cbase = wave * 64;

    const unsigned short* aptr[2];
    #pragma unroll
    for (int nt = 0; nt < 2; ++nt) {
        int row = mbase + nt * 16 + c16;
        if (row >= N_NODES) row = N_NODES - 1;
        aptr[nt] = A + (size_t)row * DIM + q * 8;
    }
    const unsigned short* wptr[4];
    #pragma unroll
    for (int ct = 0; ct < 4; ++ct)
        wptr[ct] = Bt + (size_t)(cbase + ct * 16 + c16) * DIM + q * 8;

    f32x4 acc[2][4] = {};
    // 2-deep software pipeline: load k+32 while MFMA on k
    bf16x8 nfc[2], wfc[4];
    #pragma unroll
    for (int nt = 0; nt < 2; ++nt)
        nfc[nt] = __builtin_bit_cast(bf16x8, *(const u16x8*)(aptr[nt]));
    #pragma unroll
    for (int ct = 0; ct < 4; ++ct)
        wfc[ct] = __builtin_bit_cast(bf16x8, *(const u16x8*)(wptr[ct]));

    #pragma unroll 1
    for (int k0 = 32; k0 < DIM; k0 += 32) {
        bf16x8 nfn[2], wfn[4];
        #pragma unroll
        for (int nt = 0; nt < 2; ++nt)
            nfn[nt] = __builtin_bit_cast(bf16x8, *(const u16x8*)(aptr[nt] + k0));
        #pragma unroll
        for (int ct = 0; ct < 4; ++ct)
            wfn[ct] = __builtin_bit_cast(bf16x8, *(const u16x8*)(wptr[ct] + k0));
        #pragma unroll
        for (int nt = 0; nt < 2; ++nt)
            #pragma unroll
            for (int ct = 0; ct < 4; ++ct)
                acc[nt][ct] = __builtin_amdgcn_mfma_f32_16x16x32_bf16(wfc[ct], nfc[nt], acc[nt][ct], 0, 0, 0);
        #pragma unroll
        for (int nt = 0; nt < 2; ++nt) nfc[nt] = nfn[nt];
        #pragma unroll
        for (int ct = 0; ct < 4; ++ct) wfc[ct] = wfn[ct];
    }
    #pragma unroll
    for (int nt = 0; nt < 2; ++nt)
        #pragma unroll
        for (int ct = 0; ct < 4; ++ct)
            acc[nt][ct] = __builtin_amdgcn_mfma_f32_16x16x32_bf16(wfc[ct], nfc[nt], acc[nt][ct], 0, 0, 0);

    // stage pre-bias acc as bf16 (node-major transpose via LDS)
    #pragma unroll
    for (int nt = 0; nt < 2; ++nt) {
        int row = nt * 16 + c16;
        #pragma unroll
        for (int ct = 0; ct < 4; ++ct) {
            int col = cbase + ct * 16 + q * 4;
            u16x4 pk;
            pk[0] = f2b(acc[nt][ct][0]);
            pk[1] = f2b(acc[nt][ct][1]);
            pk[2] = f2b(acc[nt][ct][2]);
            pk[3] = f2b(acc[nt][ct][3]);
            *(u16x4*)&stile[row * STRIDE + col] = pk;
        }
    }
    __syncthreads();

    // node-major drain: 8 threads per node, 32 chans each
    int r  = tid >> 3;          // node-local 0..31
    int cb = (tid & 7) * 32;    // chan base
    int node = mbase + r;
    if (node < N_NODES) {
        float h[32];
        float psum = 0.0f, psq = 0.0f;
        #pragma unroll
        for (int i = 0; i < 4; ++i) {
            const u16x8 sv = *(const u16x8*)&stile[r * STRIDE + cb + i * 8];
            const f32x4 b0 = *(const f32x4*)(bias + cb + i * 8);
            const f32x4 b1 = *(const f32x4*)(bias + cb + i * 8 + 4);
            const u16x8 hv = *(const u16x8*)(Hbf + (size_t)node * DIM + cb + i * 8);
            #pragma unroll
            for (int j = 0; j < 8; ++j) {
                float v = b2f(sv[j]) + (j < 4 ? b0[j] : b1[j - 4]);
                float hn = gelu_exact(v) + b2f(hv[j]);
                h[i * 8 + j] = hn;
                psum += hn;
                psq += hn * hn;
            }
        }
        // residual write (always)
        #pragma unroll
        for (int i = 0; i < 4; ++i) {
            u16x8 hw;
            #pragma unroll
            for (int j = 0; j < 8; ++j) hw[j] = f2b(h[i * 8 + j]);
            *(u16x8*)(Hbf + (size_t)node * DIM + cb + i * 8) = hw;
        }
        if (doLN) {
            psum += __shfl_xor(psum, 1);
            psum += __shfl_xor(psum, 2);
            psum += __shfl_xor(psum, 4);
            psq  += __shfl_xor(psq, 1);
            psq  += __shfl_xor(psq, 2);
            psq  += __shfl_xor(psq, 4);
            float mu = psum * (1.0f / DIM);
            float var = fmaxf(psq * (1.0f / DIM) - mu * mu, 0.0f);
            float rs = rsqrtf(var + EPS);
            #pragma unroll
            for (int i2 = 0; i2 < 2; ++i2) {
                int c0 = cb + i2 * 16;
                unsigned int pk[4];
                #pragma unroll
                for (int k = 0; k < 4; ++k) {
                    const f32x4 ww = *(const f32x4*)(lnw + c0 + k * 4);
                    const f32x4 lb = *(const f32x4*)(lnb + c0 + k * 4);
                    int hb = i2 * 16 + k * 4;
                    float y0 = (h[hb + 0] - mu) * rs * ww[0] + lb[0];
                    float y1 = (h[hb + 1] - mu) * rs * ww[1] + lb[1];
                    float y2 = (h[hb + 2] - mu) * rs * ww[2] + lb[2];
                    float y3 = (h[hb + 3] - mu) * rs * ww[3] + lb[3];
                    pk[k] = pack_fp8x4(y0, y1, y2, y3);
                }
                uint4 st = make_uint4(pk[0], pk[1], pk[2], pk[3]);
                *(uint4*)(Z8 + (size_t)node * DIM + c0) = st;
            }
        }
    }
}

// ---- final GEMM: out = Hbf @ post_w + post_b (fp32 out) -----------------
// 32 nodes x 256 chans per block, 2-deep K-pipeline, D[node][chan] stores.
__global__ __launch_bounds__(256, 4) void gemm_out_kernel(const unsigned short* __restrict__ A,
                                                          const unsigned short* __restrict__ Bt,
                                                          float* __restrict__ C,
                                                          const float* __restrict__ bias) {
    int tid = threadIdx.x;
    int wave = tid >> 6;
    int lane = tid & 63;
    int q = lane >> 4;
    int c16 = lane & 15;
    int mbase = blockIdx.x * 32;
    int cbase = wave * 64;

    const unsigned short* aptr[2];
    #pragma unroll
    for (int nt = 0; nt < 2; ++nt) {
        int row = mbase + nt * 16 + c16;
        if (row >= N_NODES) row = N_NODES - 1;
        aptr[nt] = A + (size_t)row * DIM + q * 8;
    }
    const unsigned short* wptr[4];
    #pragma unroll
    for (int ct = 0; ct < 4; ++ct)
        wptr[ct] = Bt + (size_t)(cbase + ct * 16 + c16) * DIM + q * 8;

    f32x4 acc[2][4] = {};
    bf16x8 nfc[2], wfc[4];
    #pragma unroll
    for (int nt = 0; nt < 2; ++nt)
        nfc[nt] = __builtin_bit_cast(bf16x8, *(const u16x8*)(aptr[nt]));
    #pragma unroll
    for (int ct = 0; ct < 4; ++ct)
        wfc[ct] = __builtin_bit_cast(bf16x8, *(const u16x8*)(wptr[ct]));

    #pragma unroll 1
    for (int k0 = 32; k0 < DIM; k0 += 32) {
        bf16x8 nfn[2], wfn[4];
        #pragma unroll
        for (int nt = 0; nt < 2; ++nt)
            nfn[nt] = __builtin_bit_cast(bf16x8, *(const u16x8*)(aptr[nt] + k0));
        #pragma unroll
        for (int ct = 0; ct < 4; ++ct)
            wfn[ct] = __builtin_bit_cast(bf16x8, *(const u16x8*)(wptr[ct] + k0));
        #pragma unroll
        for (int nt = 0; nt < 2; ++nt)
            #pragma unroll
            for (int ct = 0; ct < 4; ++ct)
                acc[nt][ct] = __builtin_amdgcn_mfma_f32_16x16x32_bf16(nfc[nt], wfc[ct], acc[nt][ct], 0, 0, 0);
        #pragma unroll
        for (int nt = 0; nt < 2; ++nt) nfc[nt] = nfn[nt];
        #pragma unroll
        for (int ct = 0; ct < 4; ++ct) wfc[ct] = wfn[ct];
    }
    #pragma unroll
    for (int nt = 0; nt < 2; ++nt)
        #pragma unroll
        for (int ct = 0; ct < 4; ++ct)
            acc[nt][ct] = __builtin_amdgcn_mfma_f32_16x16x32_bf16(nfc[nt], wfc[ct], acc[nt][ct], 0, 0, 0);

    float bb[4];
    #pragma unroll
    for (int ct = 0; ct < 4; ++ct)
        bb[ct] = bias[cbase + ct * 16 + c16];
    #pragma unroll
    for (int nt = 0; nt < 2; ++nt) {
        #pragma unroll
        for (int j = 0; j < 4; ++j) {
            int node = mbase + nt * 16 + q * 4 + j;
            if (node >= N_NODES) continue;
            #pragma unroll
            for (int ct = 0; ct < 4; ++ct) {
                int chan = cbase + ct * 16 + c16;
                C[(size_t)node * DIM + chan] = acc[nt][ct][j] + bb[ct];
            }
        }
    }
}

// ---- launch -------------------------------------------------------------
extern "C" void kernel_launch(void* const* d_in, const int* in_sizes, int n_in,
                              void* d_out, int out_size, void* d_ws, size_t ws_size,
                              hipStream_t stream) {
    const int*   ei     = (const int*)d_in[1];
    const int*   src    = ei;
    const int*   dst    = ei + N_EDGES;
    const float* ew     = (const float*)d_in[2];
    const float* emb    = (const float*)d_in[3];
    const float* ln_w   = (const float*)d_in[4];
    const float* ln_b   = (const float*)d_in[5];
    const float* conv_w = (const float*)d_in[6];
    const float* conv_b = (const float*)d_in[7];
    const float* post_w = (const float*)d_in[8];
    const float* post_b = (const float*)d_in[9];
    float* out = (float*)d_out;

    char* w = (char*)d_ws;
    size_t off = 0;
    auto alloc = [&](size_t bytes) -> char* {
        char* p = w + off;
        off += (bytes + 255) & ~(size_t)255;
        return p;
    };
    unsigned long long* cnt64 = (unsigned long long*)alloc((size_t)N_NODES * 8);
    float* dinv   = (float*)alloc((size_t)N_NODES * 4);
    int*   rank   = (int*)alloc((size_t)N_EDGES * 4);
    int*   rowptr = (int*)alloc((size_t)(N_NODES + 1) * 4);
    int*   bsum   = (int*)alloc(256 * 4);
    int*   boff   = (int*)alloc(256 * 4);
    int2*  epack  = (int2*)alloc((size_t)EPACK_CAP * 8);
    unsigned short* Wt    = (unsigned short*)alloc((size_t)5 * 65536 * 2);
    unsigned short* AGG16 = (unsigned short*)alloc((size_t)N_NODES * DIM * 2);
    unsigned char*  Z8    = (unsigned char*)alloc((size_t)N_NODES * DIM);
    unsigned short* Hbf   = (unsigned short*)alloc((size_t)N_NODES * DIM * 2);

    hipMemsetAsync(cnt64, 0, (size_t)N_NODES * 8, stream);
    hipMemsetAsync(epack, 0, (size_t)EPACK_CAP * 8, stream);
    hist_kernel<<<N_EDGES / 256, 256, 0, stream>>>(dst, ew, cnt64, rank);
    scan_a_kernel<<<SCAN_B, 256, 0, stream>>>(cnt64, dinv, bsum);
    scan_b_kernel<<<1, 256, 0, stream>>>(bsum, boff, rowptr);
    scan_c_kernel<<<SCAN_B, 256, 0, stream>>>(cnt64, boff, rowptr);
    fill_kernel<<<N_EDGES / 256, 256, 0, stream>>>(src, dst, ew, dinv, rowptr, rank, epack);
    convw_kernel<<<(5 * 65536) / 256, 256, 0, stream>>>(conv_w, post_w, Wt);

    const int GEMM_GRID = (N_NODES + 31) / 32;  // 1563
    ln_cast_kernel<<<N_NODES / 4, 256, 0, stream>>>(emb, ln_w, ln_b, Z8, Hbf);
    for (int l = 0; l < NLAYERS; ++l) {
        agg_kernel<<<N_NODES / 4, 256, 0, stream>>>(Z8, rowptr, epack, dinv, AGG16);
        int doLN = (l < NLAYERS - 1) ? 1 : 0;
        const float* nlw = doLN ? (ln_w + (l + 1) * DIM) : ln_w;
        const float* nlb = doLN ? (ln_b + (l + 1) * DIM) : ln_b;
        gemm_fused_kernel<<<GEMM_GRID, 256, 0, stream>>>(AGG16, Wt + (size_t)l * 65536,
                                                         conv_b + (size_t)l * DIM, Hbf,
                                                         nlw, nlb, Z8, doLN);
    }
    gemm_out_kernel<<<GEMM_GRID, 256, 0, stream>>>(Hbf, Wt + (size_t)4 * 65536, out, post_b);
}

// Round 4
// 567.016 us; speedup vs baseline: 1.2578x; 1.1522x over previous
//
#include <hip/hip_runtime.h>
#include <hip/hip_bf16.h>

#define N_NODES 50000
#define N_EDGES 800000
#define DIM     256
#define NLAYERS 4
#define EPS     1e-5f
#define SCAN_B  196   // ceil(50000/256)
#define MASK40  ((1ULL << 40) - 1)
#define EPACK_CAP (N_EDGES + 15 * N_NODES + 32)   // CSR padded to 16
#define STRIDE  260   // LDS row stride (elems): 256 + 4 pad
#define KSTRIDE (N_NODES * 32)   // elems per ks-plane in fragment-major AGG

typedef __bf16 bf16x8 __attribute__((ext_vector_type(8)));
typedef float  f32x4  __attribute__((ext_vector_type(4)));
typedef float  f32x2  __attribute__((ext_vector_type(2)));
typedef unsigned short u16x8 __attribute__((ext_vector_type(8)));
typedef unsigned short u16x4 __attribute__((ext_vector_type(4)));
typedef int            i32x4 __attribute__((ext_vector_type(4)));
typedef unsigned int   u32x2 __attribute__((ext_vector_type(2)));

__device__ __forceinline__ unsigned short f2b(float f) {
    __hip_bfloat16 h = __float2bfloat16(f);
    return __builtin_bit_cast(unsigned short, h);
}
__device__ __forceinline__ float b2f(unsigned short u) {
    unsigned int v = ((unsigned int)u) << 16;
    return __builtin_bit_cast(float, v);
}
// exact-GELU via Abramowitz-Stegun 7.1.26 erf (|erf err| <= 1.5e-7,
// far below bf16 rounding). ~20 VALU ops, no divergent branch.
__device__ __forceinline__ float gelu_exact(float x) {
    float ax = fabsf(x) * 0.70710678118654752f;
    float t  = 1.0f / (1.0f + 0.3275911f * ax);
    float p  = t * (0.254829592f + t * (-0.284496736f +
               t * (1.421413741f + t * (-1.453152027f + t * 1.061405429f))));
    float er = 1.0f - p * __expf(-ax * ax);
    er = (x < 0.0f) ? -er : er;
    return 0.5f * x * (1.0f + er);
}
// pack 4 f32 -> 4 fp8 e4m3 (OCP on gfx950), RNE
__device__ __forceinline__ unsigned int pack_fp8x4(float a, float b, float c, float d) {
    int v = 0;
    v = __builtin_amdgcn_cvt_pk_fp8_f32(a, b, v, false);
    v = __builtin_amdgcn_cvt_pk_fp8_f32(c, d, v, true);
    return (unsigned int)v;
}

// ---- setup kernels ------------------------------------------------------
__global__ __launch_bounds__(256) void hist_kernel(const int* __restrict__ dst,
                                                   const float* __restrict__ w,
                                                   unsigned long long* __restrict__ cnt64,
                                                   int* __restrict__ rank) {
    int e = blockIdx.x * 256 + threadIdx.x;
    if (e >= N_EDGES) return;
    int d = dst[e];
    unsigned long long wfix = (unsigned long long)(w[e] * 4294967296.0f);
    unsigned long long old = atomicAdd(&cnt64[d], (1ULL << 40) | wfix);
    rank[e] = (int)(old >> 40);
}

__global__ __launch_bounds__(256) void scan_a_kernel(const unsigned long long* __restrict__ cnt64,
                                                     float* __restrict__ dinv,
                                                     int* __restrict__ bsum) {
    __shared__ int l[256];
    int i = blockIdx.x * 256 + threadIdx.x;
    int pc = 0;
    if (i < N_NODES) {
        unsigned long long v = cnt64[i];
        int cnt = (int)(v >> 40);
        float sw = (float)(v & MASK40) * 2.3283064365386963e-10f;  // *2^-32
        dinv[i] = rsqrtf(1.0f + sw);
        pc = (cnt + 15) & ~15;
    }
    l[threadIdx.x] = pc;
    __syncthreads();
    for (int o = 128; o > 0; o >>= 1) {
        if (threadIdx.x < o) l[threadIdx.x] += l[threadIdx.x + o];
        __syncthreads();
    }
    if (threadIdx.x == 0) bsum[blockIdx.x] = l[0];
}

__global__ __launch_bounds__(256) void scan_b_kernel(const int* __restrict__ bsum,
                                                     int* __restrict__ boff,
                                                     int* __restrict__ rowptr) {
    __shared__ int l[256];
    int t = threadIdx.x;
    l[t] = (t < SCAN_B) ? bsum[t] : 0;
    __syncthreads();
    if (t == 0) {
        int run = 0;
        for (int j = 0; j < SCAN_B; ++j) { int v = l[j]; l[j] = run; run += v; }
        rowptr[N_NODES] = run;
    }
    __syncthreads();
    boff[t] = l[t];
}

__global__ __launch_bounds__(256) void scan_c_kernel(const unsigned long long* __restrict__ cnt64,
                                                     const int* __restrict__ boff,
                                                     int* __restrict__ rowptr) {
    __shared__ int l[256];
    int i = blockIdx.x * 256 + threadIdx.x;
    int pc = 0;
    if (i < N_NODES) {
        int cnt = (int)(cnt64[i] >> 40);
        pc = (cnt + 15) & ~15;
    }
    l[threadIdx.x] = pc;
    __syncthreads();
    if (threadIdx.x == 0) {
        int run = 0;
        for (int j = 0; j < 256; ++j) { int v = l[j]; l[j] = run; run += v; }
    }
    __syncthreads();
    if (i < N_NODES) rowptr[i] = boff[blockIdx.x] + l[threadIdx.x];
}

// No atomics: position = rowptr[dst] + rank.  epack.x = src byte-offset (src*256, fp8 rows).
__global__ __launch_bounds__(256) void fill_kernel(const int* __restrict__ src,
                                                   const int* __restrict__ dst,
                                                   const float* __restrict__ w,
                                                   const float* __restrict__ dinv,
                                                   const int* __restrict__ rowptr,
                                                   const int* __restrict__ rank,
                                                   int2* __restrict__ epack) {
    int e = blockIdx.x * 256 + threadIdx.x;
    if (e >= N_EDGES) return;
    int s = src[e], d = dst[e];
    float c = dinv[s] * w[e] * dinv[d];
    int p = rowptr[d] + rank[e];
    epack[p] = make_int2(s << 8, __float_as_int(c));
}

// Fragment-major weights: Wt[m][ks][n][ke], ks=K-step(32), n=out chan, ke=k%32.
// A wave's wf fragment load (16 consecutive chans x 64B) is 1KB contiguous.
__global__ __launch_bounds__(256) void convw_kernel(const float* __restrict__ conv_w,
                                                    const float* __restrict__ post_w,
                                                    unsigned short* __restrict__ Wt) {
    int idx = blockIdx.x * 256 + threadIdx.x;
    if (idx >= 5 * 65536) return;
    int m  = idx >> 16;
    int r  = idx & 65535;
    int ks = r >> 13;          // 0..7
    int n  = (r >> 5) & 255;   // out chan
    int ke = r & 31;           // k within step
    int k  = ks * 32 + ke;
    float v = (m < 4) ? conv_w[m * 65536 + k * 256 + n] : post_w[k * 256 + n];
    Wt[idx] = f2b(v);
}

// ---- per-layer kernels --------------------------------------------------
// wave-per-row: Z8 = fp8(LN0(emb)), Hbf = bf16(emb)  (used once)
__global__ __launch_bounds__(256) void ln_cast_kernel(const float* __restrict__ H,
                                                      const float* __restrict__ lnw,
                                                      const float* __restrict__ lnb,
                                                      unsigned char* __restrict__ Z8,
                                                      unsigned short* __restrict__ Hbf) {
    int row = blockIdx.x * 4 + (threadIdx.x >> 6);
    int lane = threadIdx.x & 63;
    const float4 x = *(const float4*)(H + (size_t)row * DIM + lane * 4);
    float s = x.x + x.y + x.z + x.w;
    for (int o = 32; o > 0; o >>= 1) s += __shfl_xor(s, o);
    float mu = s * (1.0f / DIM);
    float d0 = x.x - mu, d1 = x.y - mu, d2 = x.z - mu, d3 = x.w - mu;
    float v = d0 * d0 + d1 * d1 + d2 * d2 + d3 * d3;
    for (int o = 32; o > 0; o >>= 1) v += __shfl_xor(v, o);
    float rs = rsqrtf(v * (1.0f / DIM) + EPS);
    const float4 ww = *(const float4*)(lnw + lane * 4);
    const float4 bb = *(const float4*)(lnb + lane * 4);
    float z0 = d0 * rs * ww.x + bb.x;
    float z1 = d1 * rs * ww.y + bb.y;
    float z2 = d2 * rs * ww.z + bb.z;
    float z3 = d3 * rs * ww.w + bb.w;
    *(unsigned int*)(Z8 + (size_t)row * DIM + lane * 4) = pack_fp8x4(z0, z1, z2, z3);
    ushort4 h4;
    h4.x = f2b(x.x); h4.y = f2b(x.y); h4.z = f2b(x.z); h4.w = f2b(x.w);
    *(ushort4*)(Hbf + (size_t)row * DIM + lane * 4) = h4;
}

// Pure gather-aggregate: AGGt[ks][dst][32] = sum coef * Z8[src] (+ self-loop).
// Output written in fragment-major layout for the GEMM's coalesced A loads.
__global__ __launch_bounds__(256) void agg_kernel(const unsigned char* __restrict__ Z8,
                                                  const int* __restrict__ rowptr,
                                                  const int2* __restrict__ epack,
                                                  const float* __restrict__ dinv,
                                                  unsigned short* __restrict__ AGG) {
    int node = blockIdx.x * 4 + (threadIdx.x >> 6);
    int lane = threadIdx.x & 63;
    int g = lane >> 5;           // half id
    int colB = (lane & 31) * 8;  // elem (== byte) offset of this lane's 8 fp8 elems

    float di = dinv[node];
    float scg = (g == 0) ? di * di : 0.0f;   // self-loop only in half 0
    const u32x2 zs = *(const u32x2*)(Z8 + (size_t)node * DIM + colB);
    f32x2 a0, a1, a2, a3;
    {
        f32x2 p0 = __builtin_amdgcn_cvt_pk_f32_fp8(zs[0], false);
        f32x2 p1 = __builtin_amdgcn_cvt_pk_f32_fp8(zs[0], true);
        f32x2 p2 = __builtin_amdgcn_cvt_pk_f32_fp8(zs[1], false);
        f32x2 p3 = __builtin_amdgcn_cvt_pk_f32_fp8(zs[1], true);
        a0 = scg * p0; a1 = scg * p1; a2 = scg * p2; a3 = scg * p3;
    }

    int e0 = rowptr[node], e1 = rowptr[node + 1];
    for (int e = e0; e < e1; e += 16) {
        const int2* pp = epack + e + 8 * g;
        const i32x4 q0 = *(const i32x4*)pp;        // edges 0,1
        const i32x4 q1 = *(const i32x4*)(pp + 2);  // edges 2,3
        const i32x4 q2 = *(const i32x4*)(pp + 4);  // edges 4,5
        const i32x4 q3 = *(const i32x4*)(pp + 6);  // edges 6,7
        const u32x2 v0 = *(const u32x2*)(Z8 + q0[0] + colB);
        const u32x2 v1 = *(const u32x2*)(Z8 + q0[2] + colB);
        const u32x2 v2 = *(const u32x2*)(Z8 + q1[0] + colB);
        const u32x2 v3 = *(const u32x2*)(Z8 + q1[2] + colB);
        const u32x2 v4 = *(const u32x2*)(Z8 + q2[0] + colB);
        const u32x2 v5 = *(const u32x2*)(Z8 + q2[2] + colB);
        const u32x2 v6 = *(const u32x2*)(Z8 + q3[0] + colB);
        const u32x2 v7 = *(const u32x2*)(Z8 + q3[2] + colB);
        float c0 = __int_as_float(q0[1]), c1 = __int_as_float(q0[3]);
        float c2 = __int_as_float(q1[1]), c3 = __int_as_float(q1[3]);
        float c4 = __int_as_float(q2[1]), c5 = __int_as_float(q2[3]);
        float c6 = __int_as_float(q3[1]), c7 = __int_as_float(q3[3]);
        #pragma unroll
        for (int h = 0; h < 8; ++h) {
            u32x2 vv; float cc;
            switch (h) {
                case 0: vv = v0; cc = c0; break;
                case 1: vv = v1; cc = c1; break;
                case 2: vv = v2; cc = c2; break;
                case 3: vv = v3; cc = c3; break;
                case 4: vv = v4; cc = c4; break;
                case 5: vv = v5; cc = c5; break;
                case 6: vv = v6; cc = c6; break;
                default: vv = v7; cc = c7; break;
            }
            f32x2 p0 = __builtin_amdgcn_cvt_pk_f32_fp8(vv[0], false);
            f32x2 p1 = __builtin_amdgcn_cvt_pk_f32_fp8(vv[0], true);
            f32x2 p2 = __builtin_amdgcn_cvt_pk_f32_fp8(vv[1], false);
            f32x2 p3 = __builtin_amdgcn_cvt_pk_f32_fp8(vv[1], true);
            a0 += cc * p0; a1 += cc * p1; a2 += cc * p2; a3 += cc * p3;
        }
    }
    float a[8] = {a0[0], a0[1], a1[0], a1[1], a2[0], a2[1], a3[0], a3[1]};
    #pragma unroll
    for (int j = 0; j < 8; ++j) a[j] += __shfl_xor(a[j], 32);

    if (g == 0) {
        u16x8 z;
        #pragma unroll
        for (int j = 0; j < 8; ++j) z[j] = f2b(a[j]);
        int ks  = colB >> 5;   // K-step plane
        int off = colB & 31;   // elem within step
        *(u16x8*)(AGG + (size_t)ks * KSTRIDE + node * 32 + off) = z;
    }
}

// ---- fused GEMM: 32 nodes x 256 chans per block (grid 1563).
// Fragment-major A (AGGt) and W (Wt): every K-loop load is 1KB contiguous
// per wave. Full K unroll. LDS transpose -> 8-threads-per-node epilogue.
__global__ __launch_bounds__(256, 4) void gemm_fused_kernel(const unsigned short* __restrict__ A,
                                                            const unsigned short* __restrict__ Bt,
                                                            const float* __restrict__ bias,
                                                            unsigned short* __restrict__ Hbf,
                                                            const float* __restrict__ lnw,
                                                            const float* __restrict__ lnb,
                                                            unsigned char* __restrict__ Z8,
                                                            int doLN) {
    __shared__ unsigned short stile[32 * STRIDE];   // 16.6 KB, bf16 pre-bias acc
    int tid = threadIdx.x;
    int wave = tid >> 6;
    int lane = tid & 63;
    int q = lane >> 4;
    int c16 = lane & 15;
    int mbase = blockIdx.x * 32;
    int cbase = wave * 64;

    // per-lane element offsets within each ks-plane
    int aoff[2];
    #pragma unroll
    for (int nt = 0; nt < 2; ++nt) {
        int row = mbase + nt * 16 + c16;
        if (row >= N_NODES) row = N_NODES - 1;
        aoff[nt] = row * 32 + q * 8;
    }
    int woff[4];
    #pragma unroll
    for (int ct = 0; ct < 4; ++ct)
        woff[ct] = (cbase + ct * 16 + c16) * 32 + q * 8;

    f32x4 acc[2][4] = {};
    #pragma unroll
    for (int ks = 0; ks < 8; ++ks) {
        bf16x8 nf[2], wf[4];
        #pragma unroll
        for (int nt = 0; nt < 2; ++nt)
            nf[nt] = __builtin_bit_cast(bf16x8, *(const u16x8*)(A + (size_t)ks * KSTRIDE + aoff[nt]));
        #pragma unroll
        for (int ct = 0; ct < 4; ++ct)
            wf[ct] = __builtin_bit_cast(bf16x8, *(const u16x8*)(Bt + ks * 8192 + woff[ct]));
        #pragma unroll
        for (int nt = 0; nt < 2; ++nt)
            #pragma unroll
            for (int ct = 0; ct < 4; ++ct)
                acc[nt][ct] = __builtin_amdgcn_mfma_f32_16x16x32_bf16(wf[ct], nf[nt], acc[nt][ct], 0, 0, 0);
    }

    // stage pre-bias acc as bf16 (node-major transpose via LDS)
    #pragma unroll
    for (int nt = 0; nt < 2; ++nt) {
        int row = nt * 16 + c16;
        #pragma unroll
        for (int ct = 0; ct < 4; ++ct) {
            int col = cbase + ct * 16 + q * 4;
            u16x4 pk;
            pk[0] = f2b(acc[nt][ct][0]);
            pk[1] = f2b(acc[nt][ct][1]);
            pk[2] = f2b(acc[nt][ct][2]);
            pk[3] = f2b(acc[nt][ct][3]);
            *(u16x4*)&stile[row * STRIDE + col] = pk;
        }
    }
    __syncthreads();

    // node-major drain: 8 threads per node, 32 chans each
    int r  = tid >> 3;          // node-local 0..31
    int cb = (tid & 7) * 32;    // chan base
    int node = mbase + r;
    if (node < N_NODES) {
        float h[32];
        float psum = 0.0f, psq = 0.0f;
        #pragma unroll
        for (int i = 0; i < 4; ++i) {
            const u16x8 sv = *(const u16x8*)&stile[r * STRIDE + cb + i * 8];
            const f32x4 b0 = *(const f32x4*)(bias + cb + i * 8);
            const f32x4 b1 = *(const f32x4*)(bias + cb + i * 8 + 4);
            const u16x8 hv = *(const u16x8*)(Hbf + (size_t)node * DIM + cb + i * 8);
            #pragma unroll
            for (int j = 0; j < 8; ++j) {
                float v = b2f(sv[j]) + (j < 4 ? b0[j] : b1[j - 4]);
                float hn = gelu_exact(v) + b2f(hv[j]);
                h[i * 8 + j] = hn;
                psum += hn;
                psq += hn * hn;
            }
        }
        // residual write (always)
        #pragma unroll
        for (int i = 0; i < 4; ++i) {
            u16x8 hw;
            #pragma unroll
            for (int j = 0; j < 8; ++j) hw[j] = f2b(h[i * 8 + j]);
            *(u16x8*)(Hbf + (size_t)node * DIM + cb + i * 8) = hw;
        }
        if (doLN) {
            psum += __shfl_xor(psum, 1);
            psum += __shfl_xor(psum, 2);
            psum += __shfl_xor(psum, 4);
            psq  += __shfl_xor(psq, 1);
            psq  += __shfl_xor(psq, 2);
            psq  += __shfl_xor(psq, 4);
            float mu = psum * (1.0f / DIM);
            float var = fmaxf(psq * (1.0f / DIM) - mu * mu, 0.0f);
            float rs = rsqrtf(var + EPS);
            #pragma unroll
            for (int i2 = 0; i2 < 2; ++i2) {
                int c0 = cb + i2 * 16;
                unsigned int pk[4];
                #pragma unroll
                for (int k = 0; k < 4; ++k) {
                    const f32x4 ww = *(const f32x4*)(lnw + c0 + k * 4);
                    const f32x4 lb = *(const f32x4*)(lnb + c0 + k * 4);
                    int hb = i2 * 16 + k * 4;
                    float y0 = (h[hb + 0] - mu) * rs * ww[0] + lb[0];
                    float y1 = (h[hb + 1] - mu) * rs * ww[1] + lb[1];
                    float y2 = (h[hb + 2] - mu) * rs * ww[2] + lb[2];
                    float y3 = (h[hb + 3] - mu) * rs * ww[3] + lb[3];
                    pk[k] = pack_fp8x4(y0, y1, y2, y3);
                }
                uint4 st = make_uint4(pk[0], pk[1], pk[2], pk[3]);
                *(uint4*)(Z8 + (size_t)node * DIM + c0) = st;
            }
        }
    }
}

// ---- final GEMM: out = Hbf @ post_w + post_b (fp32 out) -----------------
// A = Hbf (node-major), W fragment-major. D[node][chan] stores.
__global__ __launch_bounds__(256, 4) void gemm_out_kernel(const unsigned short* __restrict__ A,
                                                          const unsigned short* __restrict__ Bt,
                                                          float* __restrict__ C,
                                                          const float* __restrict__ bias) {
    int tid = threadIdx.x;
    int wave = tid >> 6;
    int lane = tid & 63;
    int q = lane >> 4;
    int c16 = lane & 15;
    int mbase = blockIdx.x * 32;
    int cbase = wave * 64;

    const unsigned short* aptr[2];
    #pragma unroll
    for (int nt = 0; nt < 2; ++nt) {
        int row = mbase + nt * 16 + c16;
        if (row >= N_NODES) row = N_NODES - 1;
        aptr[nt] = A + (size_t)row * DIM + q * 8;
    }
    int woff[4];
    #pragma unroll
    for (int ct = 0; ct < 4; ++ct)
        woff[ct] = (cbase + ct * 16 + c16) * 32 + q * 8;

    f32x4 acc[2][4] = {};
    #pragma unroll
    for (int ks = 0; ks < 8; ++ks) {
        bf16x8 nf[2], wf[4];
        #pragma unroll
        for (int nt = 0; nt < 2; ++nt)
            nf[nt] = __builtin_bit_cast(bf16x8, *(const u16x8*)(aptr[nt] + ks * 32));
        #pragma unroll
        for (int ct = 0; ct < 4; ++ct)
            wf[ct] = __builtin_bit_cast(bf16x8, *(const u16x8*)(Bt + ks * 8192 + woff[ct]));
        #pragma unroll
        for (int nt = 0; nt < 2; ++nt)
            #pragma unroll
            for (int ct = 0; ct < 4; ++ct)
                acc[nt][ct] = __builtin_amdgcn_mfma_f32_16x16x32_bf16(nf[nt], wf[ct], acc[nt][ct], 0, 0, 0);
    }

    float bb[4];
    #pragma unroll
    for (int ct = 0; ct < 4; ++ct)
        bb[ct] = bias[cbase + ct * 16 + c16];
    #pragma unroll
    for (int nt = 0; nt < 2; ++nt) {
        #pragma unroll
        for (int j = 0; j < 4; ++j) {
            int node = mbase + nt * 16 + q * 4 + j;
            if (node >= N_NODES) continue;
            #pragma unroll
            for (int ct = 0; ct < 4; ++ct) {
                int chan = cbase + ct * 16 + c16;
                C[(size_t)node * DIM + chan] = acc[nt][ct][j] + bb[ct];
            }
        }
    }
}

// ---- launch -------------------------------------------------------------
extern "C" void kernel_launch(void* const* d_in, const int* in_sizes, int n_in,
                              void* d_out, int out_size, void* d_ws, size_t ws_size,
                              hipStream_t stream) {
    const int*   ei     = (const int*)d_in[1];
    const int*   src    = ei;
    const int*   dst    = ei + N_EDGES;
    const float* ew     = (const float*)d_in[2];
    const float* emb    = (const float*)d_in[3];
    const float* ln_w   = (const float*)d_in[4];
    const float* ln_b   = (const float*)d_in[5];
    const float* conv_w = (const float*)d_in[6];
    const float* conv_b = (const float*)d_in[7];
    const float* post_w = (const float*)d_in[8];
    const float* post_b = (const float*)d_in[9];
    float* out = (float*)d_out;

    char* w = (char*)d_ws;
    size_t off = 0;
    auto alloc = [&](size_t bytes) -> char* {
        char* p = w + off;
        off += (bytes + 255) & ~(size_t)255;
        return p;
    };
    unsigned long long* cnt64 = (unsigned long long*)alloc((size_t)N_NODES * 8);
    float* dinv   = (float*)alloc((size_t)N_NODES * 4);
    int*   rank   = (int*)alloc((size_t)N_EDGES * 4);
    int*   rowptr = (int*)alloc((size_t)(N_NODES + 1) * 4);
    int*   bsum   = (int*)alloc(256 * 4);
    int*   boff   = (int*)alloc(256 * 4);
    int2*  epack  = (int2*)alloc((size_t)EPACK_CAP * 8);
    unsigned short* Wt    = (unsigned short*)alloc((size_t)5 * 65536 * 2);
    unsigned short* AGG16 = (unsigned short*)alloc((size_t)N_NODES * DIM * 2);
    unsigned char*  Z8    = (unsigned char*)alloc((size_t)N_NODES * DIM);
    unsigned short* Hbf   = (unsigned short*)alloc((size_t)N_NODES * DIM * 2);

    hipMemsetAsync(cnt64, 0, (size_t)N_NODES * 8, stream);
    hipMemsetAsync(epack, 0, (size_t)EPACK_CAP * 8, stream);
    hist_kernel<<<N_EDGES / 256, 256, 0, stream>>>(dst, ew, cnt64, rank);
    scan_a_kernel<<<SCAN_B, 256, 0, stream>>>(cnt64, dinv, bsum);
    scan_b_kernel<<<1, 256, 0, stream>>>(bsum, boff, rowptr);
    scan_c_kernel<<<SCAN_B, 256, 0, stream>>>(cnt64, boff, rowptr);
    fill_kernel<<<N_EDGES / 256, 256, 0, stream>>>(src, dst, ew, dinv, rowptr, rank, epack);
    convw_kernel<<<(5 * 65536) / 256, 256, 0, stream>>>(conv_w, post_w, Wt);

    const int GEMM_GRID = (N_NODES + 31) / 32;  // 1563
    ln_cast_kernel<<<N_NODES / 4, 256, 0, stream>>>(emb, ln_w, ln_b, Z8, Hbf);
    for (int l = 0; l < NLAYERS; ++l) {
        agg_kernel<<<N_NODES / 4, 256, 0, stream>>>(Z8, rowptr, epack, dinv, AGG16);
        int doLN = (l < NLAYERS - 1) ? 1 : 0;
        const float* nlw = doLN ? (ln_w + (l + 1) * DIM) : ln_w;
        const float* nlb = doLN ? (ln_b + (l + 1) * DIM) : ln_b;
        gemm_fused_kernel<<<GEMM_GRID, 256, 0, stream>>>(AGG16, Wt + (size_t)l * 65536,
                                                         conv_b + (size_t)l * DIM, Hbf,
                                                         nlw, nlb, Z8, doLN);
    }
    gemm_out_kernel<<<GEMM_GRID, 256, 0, stream>>>(Hbf, Wt + (size_t)4 * 65536, out, post_b);
}

// Round 5
// 564.304 us; speedup vs baseline: 1.2638x; 1.0048x over previous
//
#include <hip/hip_runtime.h>
#include <hip/hip_bf16.h>

#define N_NODES 50000
#define N_EDGES 800000
#define DIM     256
#define NLAYERS 4
#define EPS     1e-5f
#define SCAN_B  196   // ceil(50000/256)
#define MASK40  ((1ULL << 40) - 1)
#define EPACK_CAP (N_EDGES + 15 * N_NODES + 32)   // CSR padded to 16
#define ASTRIDE 258   // LDS A-tile row stride (elems): 256 + 2 -> <=2-way read conflicts

typedef __bf16 bf16x8 __attribute__((ext_vector_type(8)));
typedef float  f32x4  __attribute__((ext_vector_type(4)));
typedef float  f32x2  __attribute__((ext_vector_type(2)));
typedef unsigned short u16x8 __attribute__((ext_vector_type(8)));
typedef unsigned short u16x4 __attribute__((ext_vector_type(4)));
typedef int            i32x4 __attribute__((ext_vector_type(4)));
typedef unsigned int   u32x2 __attribute__((ext_vector_type(2)));

__device__ __forceinline__ unsigned short f2b(float f) {
    __hip_bfloat16 h = __float2bfloat16(f);
    return __builtin_bit_cast(unsigned short, h);
}
__device__ __forceinline__ float b2f(unsigned short u) {
    unsigned int v = ((unsigned int)u) << 16;
    return __builtin_bit_cast(float, v);
}
// exact-GELU via Abramowitz-Stegun 7.1.26 erf (|erf err| <= 1.5e-7,
// far below bf16 rounding). ~20 VALU ops, no divergent branch.
__device__ __forceinline__ float gelu_exact(float x) {
    float ax = fabsf(x) * 0.70710678118654752f;
    float t  = 1.0f / (1.0f + 0.3275911f * ax);
    float p  = t * (0.254829592f + t * (-0.284496736f +
               t * (1.421413741f + t * (-1.453152027f + t * 1.061405429f))));
    float er = 1.0f - p * __expf(-ax * ax);
    er = (x < 0.0f) ? -er : er;
    return 0.5f * x * (1.0f + er);
}
// pack 4 f32 -> 4 fp8 e4m3 (OCP on gfx950), RNE
__device__ __forceinline__ unsigned int pack_fp8x4(float a, float b, float c, float d) {
    int v = 0;
    v = __builtin_amdgcn_cvt_pk_fp8_f32(a, b, v, false);
    v = __builtin_amdgcn_cvt_pk_fp8_f32(c, d, v, true);
    return (unsigned int)v;
}

// ---- setup kernels ------------------------------------------------------
__global__ __launch_bounds__(256) void hist_kernel(const int* __restrict__ dst,
                                                   const float* __restrict__ w,
                                                   unsigned long long* __restrict__ cnt64,
                                                   int* __restrict__ rank) {
    int e = blockIdx.x * 256 + threadIdx.x;
    if (e >= N_EDGES) return;
    int d = dst[e];
    unsigned long long wfix = (unsigned long long)(w[e] * 4294967296.0f);
    unsigned long long old = atomicAdd(&cnt64[d], (1ULL << 40) | wfix);
    rank[e] = (int)(old >> 40);
}

__global__ __launch_bounds__(256) void scan_a_kernel(const unsigned long long* __restrict__ cnt64,
                                                     float* __restrict__ dinv,
                                                     int* __restrict__ bsum) {
    __shared__ int l[256];
    int i = blockIdx.x * 256 + threadIdx.x;
    int pc = 0;
    if (i < N_NODES) {
        unsigned long long v = cnt64[i];
        int cnt = (int)(v >> 40);
        float sw = (float)(v & MASK40) * 2.3283064365386963e-10f;  // *2^-32
        dinv[i] = rsqrtf(1.0f + sw);
        pc = (cnt + 15) & ~15;
    }
    l[threadIdx.x] = pc;
    __syncthreads();
    for (int o = 128; o > 0; o >>= 1) {
        if (threadIdx.x < o) l[threadIdx.x] += l[threadIdx.x + o];
        __syncthreads();
    }
    if (threadIdx.x == 0) bsum[blockIdx.x] = l[0];
}

__global__ __launch_bounds__(256) void scan_b_kernel(const int* __restrict__ bsum,
                                                     int* __restrict__ boff,
                                                     int* __restrict__ rowptr) {
    __shared__ int l[256];
    int t = threadIdx.x;
    l[t] = (t < SCAN_B) ? bsum[t] : 0;
    __syncthreads();
    if (t == 0) {
        int run = 0;
        for (int j = 0; j < SCAN_B; ++j) { int v = l[j]; l[j] = run; run += v; }
        rowptr[N_NODES] = run;
    }
    __syncthreads();
    boff[t] = l[t];
}

__global__ __launch_bounds__(256) void scan_c_kernel(const unsigned long long* __restrict__ cnt64,
                                                     const int* __restrict__ boff,
                                                     int* __restrict__ rowptr) {
    __shared__ int l[256];
    int i = blockIdx.x * 256 + threadIdx.x;
    int pc = 0;
    if (i < N_NODES) {
        int cnt = (int)(cnt64[i] >> 40);
        pc = (cnt + 15) & ~15;
    }
    l[threadIdx.x] = pc;
    __syncthreads();
    if (threadIdx.x == 0) {
        int run = 0;
        for (int j = 0; j < 256; ++j) { int v = l[j]; l[j] = run; run += v; }
    }
    __syncthreads();
    if (i < N_NODES) rowptr[i] = boff[blockIdx.x] + l[threadIdx.x];
}

// No atomics: position = rowptr[dst] + rank.  epack.x = src byte-offset (src*256, fp8 rows).
__global__ __launch_bounds__(256) void fill_kernel(const int* __restrict__ src,
                                                   const int* __restrict__ dst,
                                                   const float* __restrict__ w,
                                                   const float* __restrict__ dinv,
                                                   const int* __restrict__ rowptr,
                                                   const int* __restrict__ rank,
                                                   int2* __restrict__ epack) {
    int e = blockIdx.x * 256 + threadIdx.x;
    if (e >= N_EDGES) return;
    int s = src[e], d = dst[e];
    float c = dinv[s] * w[e] * dinv[d];
    int p = rowptr[d] + rank[e];
    epack[p] = make_int2(s << 8, __float_as_int(c));
}

// Fragment-major weights: Wt[m][ks][n][ke], ks=K-step(32), n=out chan, ke=k%32.
// A wave's wf fragment load (16 consecutive chans x 64B) is 1KB contiguous.
__global__ __launch_bounds__(256) void convw_kernel(const float* __restrict__ conv_w,
                                                    const float* __restrict__ post_w,
                                                    unsigned short* __restrict__ Wt) {
    int idx = blockIdx.x * 256 + threadIdx.x;
    if (idx >= 5 * 65536) return;
    int m  = idx >> 16;
    int r  = idx & 65535;
    int ks = r >> 13;          // 0..7
    int n  = (r >> 5) & 255;   // out chan
    int ke = r & 31;           // k within step
    int k  = ks * 32 + ke;
    float v = (m < 4) ? conv_w[m * 65536 + k * 256 + n] : post_w[k * 256 + n];
    Wt[idx] = f2b(v);
}

// ---- per-layer kernels --------------------------------------------------
// wave-per-row: Z8 = fp8(LN0(emb)), Hbf = bf16(emb)  (used once)
__global__ __launch_bounds__(256) void ln_cast_kernel(const float* __restrict__ H,
                                                      const float* __restrict__ lnw,
                                                      const float* __restrict__ lnb,
                                                      unsigned char* __restrict__ Z8,
                                                      unsigned short* __restrict__ Hbf) {
    int row = blockIdx.x * 4 + (threadIdx.x >> 6);
    int lane = threadIdx.x & 63;
    const float4 x = *(const float4*)(H + (size_t)row * DIM + lane * 4);
    float s = x.x + x.y + x.z + x.w;
    for (int o = 32; o > 0; o >>= 1) s += __shfl_xor(s, o);
    float mu = s * (1.0f / DIM);
    float d0 = x.x - mu, d1 = x.y - mu, d2 = x.z - mu, d3 = x.w - mu;
    float v = d0 * d0 + d1 * d1 + d2 * d2 + d3 * d3;
    for (int o = 32; o > 0; o >>= 1) v += __shfl_xor(v, o);
    float rs = rsqrtf(v * (1.0f / DIM) + EPS);
    const float4 ww = *(const float4*)(lnw + lane * 4);
    const float4 bb = *(const float4*)(lnb + lane * 4);
    float z0 = d0 * rs * ww.x + bb.x;
    float z1 = d1 * rs * ww.y + bb.y;
    float z2 = d2 * rs * ww.z + bb.z;
    float z3 = d3 * rs * ww.w + bb.w;
    *(unsigned int*)(Z8 + (size_t)row * DIM + lane * 4) = pack_fp8x4(z0, z1, z2, z3);
    ushort4 h4;
    h4.x = f2b(x.x); h4.y = f2b(x.y); h4.z = f2b(x.z); h4.w = f2b(x.w);
    *(ushort4*)(Hbf + (size_t)row * DIM + lane * 4) = h4;
}

// ---- fused layer: gather-agg (32 nodes -> LDS bf16) -> GEMM -> epilogue.
// agg[i] feeds only GEMM row i, so the block is self-contained. Z8 is
// double-buffered across layers (read-arbitrary / write-own race).
// Phase overlap happens ACROSS resident blocks: one block's gathers hide
// under another's MFMAs/epilogue.
__global__ __launch_bounds__(256, 4) void layer_kernel(const unsigned char* __restrict__ Z8in,
                                                       const int* __restrict__ rowptr,
                                                       const int2* __restrict__ epack,
                                                       const float* __restrict__ dinv,
                                                       const unsigned short* __restrict__ Bt,
                                                       const float* __restrict__ bias,
                                                       unsigned short* __restrict__ Hbf,
                                                       const float* __restrict__ lnw,
                                                       const float* __restrict__ lnb,
                                                       unsigned char* __restrict__ Z8out,
                                                       int doLN) {
    __shared__ unsigned short atile[32 * ASTRIDE];   // 16.5 KB: A-tile, then stile
    int tid = threadIdx.x;
    int wave = tid >> 6;
    int lane = tid & 63;
    int q = lane >> 4;
    int c16 = lane & 15;
    int g = lane >> 5;           // half id
    int colB = (lane & 31) * 8;  // elem (== byte) offset of this lane's 8 fp8 elems
    int mbase = blockIdx.x * 32;
    int cbase = wave * 64;

    // ---- phase 1: aggregate 8 nodes per wave into atile (bf16) ----
    for (int i = 0; i < 8; ++i) {
        int nl = wave * 8 + i;
        int node = mbase + nl;
        f32x2 a0 = {0.f, 0.f}, a1 = a0, a2 = a0, a3 = a0;
        if (node < N_NODES) {
            float di = dinv[node];
            float scg = (g == 0) ? di * di : 0.0f;   // self-loop only in half 0
            const u32x2 zs = *(const u32x2*)(Z8in + (size_t)node * DIM + colB);
            {
                f32x2 p0 = __builtin_amdgcn_cvt_pk_f32_fp8(zs[0], false);
                f32x2 p1 = __builtin_amdgcn_cvt_pk_f32_fp8(zs[0], true);
                f32x2 p2 = __builtin_amdgcn_cvt_pk_f32_fp8(zs[1], false);
                f32x2 p3 = __builtin_amdgcn_cvt_pk_f32_fp8(zs[1], true);
                a0 = scg * p0; a1 = scg * p1; a2 = scg * p2; a3 = scg * p3;
            }
            int e0 = rowptr[node], e1 = rowptr[node + 1];
            for (int e = e0; e < e1; e += 16) {
                const int2* pp = epack + e + 8 * g;
                const i32x4 q0 = *(const i32x4*)pp;        // edges 0,1
                const i32x4 q1 = *(const i32x4*)(pp + 2);  // edges 2,3
                const i32x4 q2 = *(const i32x4*)(pp + 4);  // edges 4,5
                const i32x4 q3 = *(const i32x4*)(pp + 6);  // edges 6,7
                const u32x2 v0 = *(const u32x2*)(Z8in + q0[0] + colB);
                const u32x2 v1 = *(const u32x2*)(Z8in + q0[2] + colB);
                const u32x2 v2 = *(const u32x2*)(Z8in + q1[0] + colB);
                const u32x2 v3 = *(const u32x2*)(Z8in + q1[2] + colB);
                const u32x2 v4 = *(const u32x2*)(Z8in + q2[0] + colB);
                const u32x2 v5 = *(const u32x2*)(Z8in + q2[2] + colB);
                const u32x2 v6 = *(const u32x2*)(Z8in + q3[0] + colB);
                const u32x2 v7 = *(const u32x2*)(Z8in + q3[2] + colB);
                float c0 = __int_as_float(q0[1]), c1 = __int_as_float(q0[3]);
                float c2 = __int_as_float(q1[1]), c3 = __int_as_float(q1[3]);
                float c4 = __int_as_float(q2[1]), c5 = __int_as_float(q2[3]);
                float c6 = __int_as_float(q3[1]), c7 = __int_as_float(q3[3]);
                #pragma unroll
                for (int h = 0; h < 8; ++h) {
                    u32x2 vv; float cc;
                    switch (h) {
                        case 0: vv = v0; cc = c0; break;
                        case 1: vv = v1; cc = c1; break;
                        case 2: vv = v2; cc = c2; break;
                        case 3: vv = v3; cc = c3; break;
                        case 4: vv = v4; cc = c4; break;
                        case 5: vv = v5; cc = c5; break;
                        case 6: vv = v6; cc = c6; break;
                        default: vv = v7; cc = c7; break;
                    }
                    f32x2 p0 = __builtin_amdgcn_cvt_pk_f32_fp8(vv[0], false);
                    f32x2 p1 = __builtin_amdgcn_cvt_pk_f32_fp8(vv[0], true);
                    f32x2 p2 = __builtin_amdgcn_cvt_pk_f32_fp8(vv[1], false);
                    f32x2 p3 = __builtin_amdgcn_cvt_pk_f32_fp8(vv[1], true);
                    a0 += cc * p0; a1 += cc * p1; a2 += cc * p2; a3 += cc * p3;
                }
            }
        }
        float a[8] = {a0[0], a0[1], a1[0], a1[1], a2[0], a2[1], a3[0], a3[1]};
        #pragma unroll
        for (int j = 0; j < 8; ++j) a[j] += __shfl_xor(a[j], 32);
        if (g == 0) {
            u16x8 z;
            #pragma unroll
            for (int j = 0; j < 8; ++j) z[j] = f2b(a[j]);
            *(u16x8*)&atile[nl * ASTRIDE + colB] = z;
        }
    }
    __syncthreads();

    // ---- phase 2: GEMM, A from LDS, W fragment-major global (L2-hot) ----
    int aoffL[2];
    #pragma unroll
    for (int nt = 0; nt < 2; ++nt)
        aoffL[nt] = (nt * 16 + c16) * ASTRIDE + q * 8;
    int woff[4];
    #pragma unroll
    for (int ct = 0; ct < 4; ++ct)
        woff[ct] = (cbase + ct * 16 + c16) * 32 + q * 8;

    f32x4 acc[2][4] = {};
    #pragma unroll
    for (int ks = 0; ks < 8; ++ks) {
        bf16x8 nf[2], wf[4];
        #pragma unroll
        for (int nt = 0; nt < 2; ++nt)
            nf[nt] = __builtin_bit_cast(bf16x8, *(const u16x8*)&atile[aoffL[nt] + ks * 32]);
        #pragma unroll
        for (int ct = 0; ct < 4; ++ct)
            wf[ct] = __builtin_bit_cast(bf16x8, *(const u16x8*)(Bt + ks * 8192 + woff[ct]));
        #pragma unroll
        for (int nt = 0; nt < 2; ++nt)
            #pragma unroll
            for (int ct = 0; ct < 4; ++ct)
                acc[nt][ct] = __builtin_amdgcn_mfma_f32_16x16x32_bf16(wf[ct], nf[nt], acc[nt][ct], 0, 0, 0);
    }
    __syncthreads();   // all A-tile reads done before stile overwrite

    // ---- phase 3: stage pre-bias acc as bf16 (node-major transpose) ----
    #pragma unroll
    for (int nt = 0; nt < 2; ++nt) {
        int row = nt * 16 + c16;
        #pragma unroll
        for (int ct = 0; ct < 4; ++ct) {
            int col = cbase + ct * 16 + q * 4;
            u16x4 pk;
            pk[0] = f2b(acc[nt][ct][0]);
            pk[1] = f2b(acc[nt][ct][1]);
            pk[2] = f2b(acc[nt][ct][2]);
            pk[3] = f2b(acc[nt][ct][3]);
            *(u16x4*)&atile[row * ASTRIDE + col] = pk;
        }
    }
    __syncthreads();

    // ---- phase 4: node-major drain: 8 threads per node, 32 chans each ----
    int r  = tid >> 3;          // node-local 0..31
    int cb = (tid & 7) * 32;    // chan base
    int node = mbase + r;
    if (node < N_NODES) {
        float h[32];
        float psum = 0.0f, psq = 0.0f;
        #pragma unroll
        for (int i = 0; i < 4; ++i) {
            const u16x8 sv = *(const u16x8*)&atile[r * ASTRIDE + cb + i * 8];
            const f32x4 b0 = *(const f32x4*)(bias + cb + i * 8);
            const f32x4 b1 = *(const f32x4*)(bias + cb + i * 8 + 4);
            const u16x8 hv = *(const u16x8*)(Hbf + (size_t)node * DIM + cb + i * 8);
            #pragma unroll
            for (int j = 0; j < 8; ++j) {
                float v = b2f(sv[j]) + (j < 4 ? b0[j] : b1[j - 4]);
                float hn = gelu_exact(v) + b2f(hv[j]);
                h[i * 8 + j] = hn;
                psum += hn;
                psq += hn * hn;
            }
        }
        // residual write (always)
        #pragma unroll
        for (int i = 0; i < 4; ++i) {
            u16x8 hw;
            #pragma unroll
            for (int j = 0; j < 8; ++j) hw[j] = f2b(h[i * 8 + j]);
            *(u16x8*)(Hbf + (size_t)node * DIM + cb + i * 8) = hw;
        }
        if (doLN) {
            psum += __shfl_xor(psum, 1);
            psum += __shfl_xor(psum, 2);
            psum += __shfl_xor(psum, 4);
            psq  += __shfl_xor(psq, 1);
            psq  += __shfl_xor(psq, 2);
            psq  += __shfl_xor(psq, 4);
            float mu = psum * (1.0f / DIM);
            float var = fmaxf(psq * (1.0f / DIM) - mu * mu, 0.0f);
            float rs = rsqrtf(var + EPS);
            #pragma unroll
            for (int i2 = 0; i2 < 2; ++i2) {
                int c0 = cb + i2 * 16;
                unsigned int pk[4];
                #pragma unroll
                for (int k = 0; k < 4; ++k) {
                    const f32x4 ww = *(const f32x4*)(lnw + c0 + k * 4);
                    const f32x4 lb = *(const f32x4*)(lnb + c0 + k * 4);
                    int hb = i2 * 16 + k * 4;
                    float y0 = (h[hb + 0] - mu) * rs * ww[0] + lb[0];
                    float y1 = (h[hb + 1] - mu) * rs * ww[1] + lb[1];
                    float y2 = (h[hb + 2] - mu) * rs * ww[2] + lb[2];
                    float y3 = (h[hb + 3] - mu) * rs * ww[3] + lb[3];
                    pk[k] = pack_fp8x4(y0, y1, y2, y3);
                }
                uint4 st = make_uint4(pk[0], pk[1], pk[2], pk[3]);
                *(uint4*)(Z8out + (size_t)node * DIM + c0) = st;
            }
        }
    }
}

// ---- final GEMM: out = Hbf @ post_w + post_b (fp32 out) -----------------
// A = Hbf (node-major), W fragment-major. D[node][chan] stores.
__global__ __launch_bounds__(256, 4) void gemm_out_kernel(const unsigned short* __restrict__ A,
                                                          const unsigned short* __restrict__ Bt,
                                                          float* __restrict__ C,
                                                          const float* __restrict__ bias) {
    int tid = threadIdx.x;
    int wave = tid >> 6;
    int lane = tid & 63;
    int q = lane >> 4;
    int c16 = lane & 15;
    int mbase = blockIdx.x * 32;
    int cbase = wave * 64;

    const unsigned short* aptr[2];
    #pragma unroll
    for (int nt = 0; nt < 2; ++nt) {
        int row = mbase + nt * 16 + c16;
        if (row >= N_NODES) row = N_NODES - 1;
        aptr[nt] = A + (size_t)row * DIM + q * 8;
    }
    int woff[4];
    #pragma unroll
    for (int ct = 0; ct < 4; ++ct)
        woff[ct] = (cbase + ct * 16 + c16) * 32 + q * 8;

    f32x4 acc[2][4] = {};
    #pragma unroll
    for (int ks = 0; ks < 8; ++ks) {
        bf16x8 nf[2], wf[4];
        #pragma unroll
        for (int nt = 0; nt < 2; ++nt)
            nf[nt] = __builtin_bit_cast(bf16x8, *(const u16x8*)(aptr[nt] + ks * 32));
        #pragma unroll
        for (int ct = 0; ct < 4; ++ct)
            wf[ct] = __builtin_bit_cast(bf16x8, *(const u16x8*)(Bt + ks * 8192 + woff[ct]));
        #pragma unroll
        for (int nt = 0; nt < 2; ++nt)
            #pragma unroll
            for (int ct = 0; ct < 4; ++ct)
                acc[nt][ct] = __builtin_amdgcn_mfma_f32_16x16x32_bf16(nf[nt], wf[ct], acc[nt][ct], 0, 0, 0);
    }

    float bb[4];
    #pragma unroll
    for (int ct = 0; ct < 4; ++ct)
        bb[ct] = bias[cbase + ct * 16 + c16];
    #pragma unroll
    for (int nt = 0; nt < 2; ++nt) {
        #pragma unroll
        for (int j = 0; j < 4; ++j) {
            int node = mbase + nt * 16 + q * 4 + j;
            if (node >= N_NODES) continue;
            #pragma unroll
            for (int ct = 0; ct < 4; ++ct) {
                int chan = cbase + ct * 16 + c16;
                C[(size_t)node * DIM + chan] = acc[nt][ct][j] + bb[ct];
            }
        }
    }
}

// ---- launch -------------------------------------------------------------
extern "C" void kernel_launch(void* const* d_in, const int* in_sizes, int n_in,
                              void* d_out, int out_size, void* d_ws, size_t ws_size,
                              hipStream_t stream) {
    const int*   ei     = (const int*)d_in[1];
    const int*   src    = ei;
    const int*   dst    = ei + N_EDGES;
    const float* ew     = (const float*)d_in[2];
    const float* emb    = (const float*)d_in[3];
    const float* ln_w   = (const float*)d_in[4];
    const float* ln_b   = (const float*)d_in[5];
    const float* conv_w = (const float*)d_in[6];
    const float* conv_b = (const float*)d_in[7];
    const float* post_w = (const float*)d_in[8];
    const float* post_b = (const float*)d_in[9];
    float* out = (float*)d_out;

    char* w = (char*)d_ws;
    size_t off = 0;
    auto alloc = [&](size_t bytes) -> char* {
        char* p = w + off;
        off += (bytes + 255) & ~(size_t)255;
        return p;
    };
    unsigned long long* cnt64 = (unsigned long long*)alloc((size_t)N_NODES * 8);
    float* dinv   = (float*)alloc((size_t)N_NODES * 4);
    int*   rank   = (int*)alloc((size_t)N_EDGES * 4);
    int*   rowptr = (int*)alloc((size_t)(N_NODES + 1) * 4);
    int*   bsum   = (int*)alloc(256 * 4);
    int*   boff   = (int*)alloc(256 * 4);
    int2*  epack  = (int2*)alloc((size_t)EPACK_CAP * 8);
    unsigned short* Wt  = (unsigned short*)alloc((size_t)5 * 65536 * 2);
    unsigned char*  Z8a = (unsigned char*)alloc((size_t)N_NODES * DIM);
    unsigned char*  Z8b = (unsigned char*)alloc((size_t)N_NODES * DIM);
    unsigned short* Hbf = (unsigned short*)alloc((size_t)N_NODES * DIM * 2);

    hipMemsetAsync(cnt64, 0, (size_t)N_NODES * 8, stream);
    hipMemsetAsync(epack, 0, (size_t)EPACK_CAP * 8, stream);
    hist_kernel<<<N_EDGES / 256, 256, 0, stream>>>(dst, ew, cnt64, rank);
    scan_a_kernel<<<SCAN_B, 256, 0, stream>>>(cnt64, dinv, bsum);
    scan_b_kernel<<<1, 256, 0, stream>>>(bsum, boff, rowptr);
    scan_c_kernel<<<SCAN_B, 256, 0, stream>>>(cnt64, boff, rowptr);
    fill_kernel<<<N_EDGES / 256, 256, 0, stream>>>(src, dst, ew, dinv, rowptr, rank, epack);
    convw_kernel<<<(5 * 65536) / 256, 256, 0, stream>>>(conv_w, post_w, Wt);

    const int GRID = (N_NODES + 31) / 32;  // 1563
    ln_cast_kernel<<<N_NODES / 4, 256, 0, stream>>>(emb, ln_w, ln_b, Z8a, Hbf);
    for (int l = 0; l < NLAYERS; ++l) {
        const unsigned char* zin  = (l & 1) ? Z8b : Z8a;
        unsigned char*       zout = (l & 1) ? Z8a : Z8b;
        int doLN = (l < NLAYERS - 1) ? 1 : 0;
        const float* nlw = doLN ? (ln_w + (l + 1) * DIM) : ln_w;
        const float* nlb = doLN ? (ln_b + (l + 1) * DIM) : ln_b;
        layer_kernel<<<GRID, 256, 0, stream>>>(zin, rowptr, epack, dinv,
                                               Wt + (size_t)l * 65536,
                                               conv_b + (size_t)l * DIM, Hbf,
                                               nlw, nlb, zout, doLN);
    }
    gemm_out_kernel<<<GRID, 256, 0, stream>>>(Hbf, Wt + (size_t)4 * 65536, out, post_b);
}